// Round 7
// baseline (439.467 us; speedup 1.0000x reference)
//
#include <hip/hip_runtime.h>
#include <math.h>

#define BB   2
#define NN   32768
#define DIN  768
#define DD   512
#define PP   16
#define MTOT (BB*NN)          // rows per side
#define MALL (2*MTOT)         // both sides
#define NCHUNK 256
#define CHUNK  (NN/NCHUNK)    // 128
#define SCALE_INV_SQRT_D 0.04419417382415922f  // 1/sqrt(512)

typedef unsigned short u16;
typedef __attribute__((ext_vector_type(8))) short bf16x8;
typedef __attribute__((ext_vector_type(4))) float f32x4;

#define MFMA(a,b,c) __builtin_amdgcn_mfma_f32_16x16x32_bf16((a),(b),(c),0,0,0)

__device__ __forceinline__ unsigned pack2bf(float a, float b) {
  union { float f; unsigned u; } x{a}, y{b};
  unsigned ra = (x.u + 0x7FFFu + ((x.u >> 16) & 1u)) >> 16;
  unsigned rb = (y.u + 0x7FFFu + ((y.u >> 16) & 1u)) >> 16;
  return ra | (rb << 16);
}
__device__ __forceinline__ u16 f2bf(float a) {
  union { float f; unsigned u; } x{a};
  return (u16)((x.u + 0x7FFFu + ((x.u >> 16) & 1u)) >> 16);
}
__device__ __forceinline__ float bf2f(u16 u) {
  union { unsigned u; float f; } x; x.u = ((unsigned)u) << 16; return x.f;
}

__device__ __forceinline__ float block_reduce_sum_256(float v, float* sred) {
  #pragma unroll
  for (int off = 32; off; off >>= 1) v += __shfl_down(v, off);
  const int lane = threadIdx.x & 63, w = threadIdx.x >> 6;
  if (lane == 0) sred[w] = v;
  __syncthreads();
  float r = sred[0] + sred[1] + sred[2] + sred[3];
  __syncthreads();
  return r;
}

// ---------- W[768][512] fp32 -> Bf fragment layout: Bf[nf*24+ks][lane] ----------
// element: n = nf*16 + (lane&15), k = ks*32 + (lane>>4)*8 + j
__global__ __launch_bounds__(64) void bf_pack_kernel(const float* __restrict__ W,
                                                     uint4* __restrict__ Bf) {
  const int bid = blockIdx.x;            // nf*24 + ks, 768 blocks
  const int nf = bid / 24, ks = bid % 24;
  const int lane = threadIdx.x;
  const int n = nf*16 + (lane & 15);
  const int kb = ks*32 + (lane >> 4)*8;
  unsigned r0 = pack2bf(W[(size_t)(kb+0)*DD + n], W[(size_t)(kb+1)*DD + n]);
  unsigned r1 = pack2bf(W[(size_t)(kb+2)*DD + n], W[(size_t)(kb+3)*DD + n]);
  unsigned r2 = pack2bf(W[(size_t)(kb+4)*DD + n], W[(size_t)(kb+5)*DD + n]);
  unsigned r3 = pack2bf(W[(size_t)(kb+6)*DD + n], W[(size_t)(kb+7)*DD + n]);
  Bf[(size_t)bid*64 + lane] = make_uint4(r0, r1, r2, r3);
}

// ---------- normalize prototypes -> pn fp32 [16][512] ----------
__global__ __launch_bounds__(256) void proto_norm_kernel(
    const float* __restrict__ prot, float* __restrict__ pn) {
  __shared__ float sred[4];
  const int p = blockIdx.x, t = threadIdx.x;
  float2 v = *(const float2*)&prot[p*DD + 2*t];
  float ss = block_reduce_sum_256(v.x*v.x + v.y*v.y, sred);
  float sc = 1.f / fmaxf(sqrtf(ss), 1e-12f);
  *(float2*)&pn[p*DD + 2*t] = make_float2(v.x*sc, v.y*sc);
}

// ---------- Wpn = W·pn^T in B-fragment layout (p as n, 16 wide), + bpn ----------
__global__ __launch_bounds__(64) void wpn_pack_kernel(
    const float* __restrict__ W, const float* __restrict__ pn,
    const float* __restrict__ bias, uint4* __restrict__ Wpnb,
    float* __restrict__ bpn) {
  const int ks = blockIdx.x, lane = threadIdx.x;
  const int p = lane & 15;
  if (ks < 24) {
    float v[8];
    #pragma unroll
    for (int j = 0; j < 8; ++j) {
      const int k = ks*32 + (lane >> 4)*8 + j;
      const float* wr = W + (size_t)k * DD;
      const float* pr = pn + p * DD;
      float s = 0.f;
      for (int d = 0; d < DD; d += 4) {
        float4 a = *(const float4*)(wr + d);
        float4 b = *(const float4*)(pr + d);
        s += a.x*b.x + a.y*b.y + a.z*b.z + a.w*b.w;
      }
      v[j] = s;
    }
    Wpnb[ks*64 + lane] = make_uint4(pack2bf(v[0],v[1]), pack2bf(v[2],v[3]),
                                    pack2bf(v[4],v[5]), pack2bf(v[6],v[7]));
  } else {
    const int seg = lane >> 4;
    float s = 0.f;
    for (int d = seg*128; d < seg*128 + 128; ++d) s += bias[d] * pn[p*DD + d];
    s += __shfl_xor(s, 16);
    s += __shfl_xor(s, 32);
    if (lane < 16) bpn[lane] = s;
  }
}

// ---------- m97-style GEMM, BOTH sides in one dispatch ----------
// grid 4096 = 1024 mb (global rows, 2 sides) x 4 nb, XCD-chunk swizzled.
// 128x128 tile, BK=64, 4 waves 64x64. B via global_load_lds from fragment-
// packed Bf (L2-resident); A fp32->bf16 reg-staged into LDS.
__global__ __launch_bounds__(256, 3) void gemm_kernel(
    const float* __restrict__ Xs, const float* __restrict__ Xl,
    const uint4* __restrict__ Bf, const uint4* __restrict__ Wpnb,
    const float* __restrict__ bias, const float* __restrict__ bpn,
    u16* __restrict__ proj, u16* __restrict__ wbufe,
    float* __restrict__ ssqp4) {
  __shared__ __align__(16) unsigned char lds[32768];   // A:0..16K, B:16K..32K
  __shared__ float ssqred[128][2];
  const int t = threadIdx.x, lane = t & 63;
  const int wid = t >> 6, wm = wid >> 1, wn = wid & 1;
  const int cl = lane & 15, cg = lane >> 4;
  const int id = blockIdx.x;
  const int swz = (id & 7) * 512 + (id >> 3);  // 4096 blocks: bijective, 8 XCD chunks
  const int mb = swz >> 2, nb = swz & 3;       // 4 nb of same mb adjacent on one XCD
  const int m0 = mb * 128, n0 = nb * 128;      // m0: GLOBAL row over both sides
  const float* Xb = (m0 < MTOT) ? Xs : Xl;     // tiles never straddle (65536 % 128 == 0)
  const int m0l = m0 & (MTOT - 1);             // side-local row base
  // A staging: thread covers rows sr+32j (j<4), k in [c8*8, c8*8+8)
  const int sr = t >> 3, c8 = t & 7;
  const float* gA[4]; int awoff[4];
  #pragma unroll
  for (int j = 0; j < 4; ++j) {
    const int row = sr + 32*j;
    gA[j] = Xb + (size_t)(m0l + row) * DIN + c8 * 8;
    // frag layout + piece-XOR swizzle (piece q=c8&3 XOR row&3) to spread banks
    awoff[j] = (((row >> 4) * 2 + (c8 >> 2)) << 10)
             + (((c8 & 3) ^ (row & 3)) << 8) + ((row & 15) << 4);
  }
  f32x4 acc[4][4] = {};
  f32x4 sacc[4] = {};
  const bool do_score = (nb == 0) && (wn == 0);
  float4 a0[4], a1[4];
  #pragma unroll
  for (int j = 0; j < 4; ++j) {
    a0[j] = *(const float4*)gA[j];
    a1[j] = *(const float4*)(gA[j] + 4);
  }
  for (int kt = 0; kt < 12; ++kt) {
    // ---- stage: B chunks via global_load_lds (linear dest), A via ds_write
    #pragma unroll
    for (int q = 0; q < 4; ++q) {
      const int c = q * 4 + wid;               // chunk = nfl*2 + ksl
      const uint4* src = Bf + ((size_t)((nb * 8 + (c >> 1)) * 24 + kt * 2 + (c & 1))) * 64 + lane;
      __builtin_amdgcn_global_load_lds(
          (const __attribute__((address_space(1))) void*)src,
          (__attribute__((address_space(3))) void*)(lds + 16384 + q * 4096 + wid * 1024),
          16, 0, 0);
    }
    #pragma unroll
    for (int j = 0; j < 4; ++j)
      *(uint4*)(lds + awoff[j]) = make_uint4(
          pack2bf(a0[j].x, a0[j].y), pack2bf(a0[j].z, a0[j].w),
          pack2bf(a1[j].x, a1[j].y), pack2bf(a1[j].z, a1[j].w));
    __syncthreads();
    // ---- prefetch next A tile (drains at end-of-compute barrier)
    if (kt < 11) {
      #pragma unroll
      for (int j = 0; j < 4; ++j) {
        a0[j] = *(const float4*)(gA[j] + (kt + 1) * 64);
        a1[j] = *(const float4*)(gA[j] + (kt + 1) * 64 + 4);
      }
    }
    // ---- compute
    #pragma unroll
    for (int ksl = 0; ksl < 2; ++ksl) {
      bf16x8 af[4], bfr[4];
      #pragma unroll
      for (int i = 0; i < 4; ++i)
        af[i] = *(const bf16x8*)(lds + ((((wm*4 + i) * 2 + ksl) << 10)
                                        + ((cg ^ (cl & 3)) << 8) + (cl << 4)));
      #pragma unroll
      for (int j2 = 0; j2 < 4; ++j2)
        bfr[j2] = *(const bf16x8*)(lds + 16384 + (((wn*4 + j2) * 2 + ksl) << 10) + lane * 16);
      #pragma unroll
      for (int i = 0; i < 4; ++i)
        #pragma unroll
        for (int j2 = 0; j2 < 4; ++j2)
          acc[i][j2] = MFMA(af[i], bfr[j2], acc[i][j2]);
      if (do_score) {
        bf16x8 wf = *(const bf16x8*)(Wpnb + (kt * 2 + ksl) * 64 + lane);
        #pragma unroll
        for (int i = 0; i < 4; ++i) sacc[i] = MFMA(af[i], wf, sacc[i]);
      }
    }
    __syncthreads();
  }
  // ---- epilogue: bias, proj bf16 store, per-row ssq partial, raw scores
  float bv[4];
  #pragma unroll
  for (int j2 = 0; j2 < 4; ++j2) bv[j2] = bias[n0 + wn*64 + j2*16 + cl];
  #pragma unroll
  for (int mi = 0; mi < 4; ++mi) {
    float sq[4] = {0.f, 0.f, 0.f, 0.f};
    #pragma unroll
    for (int rr = 0; rr < 4; ++rr) {
      const int grow = m0 + wm*64 + mi*16 + cg*4 + rr;   // global row
      u16* pr = proj + (size_t)grow * DD + n0 + wn*64 + cl;
      #pragma unroll
      for (int j2 = 0; j2 < 4; ++j2) {
        float val = acc[mi][j2][rr] + bv[j2];
        pr[j2*16] = f2bf(val);
        sq[rr] += val * val;
      }
    }
    #pragma unroll
    for (int rr = 0; rr < 4; ++rr) {
      float v = sq[rr];
      v += __shfl_xor(v, 1); v += __shfl_xor(v, 2);
      v += __shfl_xor(v, 4); v += __shfl_xor(v, 8);
      if (cl == 0) ssqred[wm*64 + mi*16 + cg*4 + rr][wn] = v;
    }
  }
  __syncthreads();
  if (t < 128) ssqp4[(size_t)(m0 + t) * 4 + nb] = ssqred[t][0] + ssqred[t][1];
  if (do_score) {
    const float bpv = bpn[cl];
    #pragma unroll
    for (int mi = 0; mi < 4; ++mi)
      #pragma unroll
      for (int rr = 0; rr < 4; ++rr) {
        const int grow = m0 + wm*64 + mi*16 + cg*4 + rr;
        const int sbp = grow >> 15, n = grow & (NN - 1);  // sbp = side*2+b in [0,4)
        wbufe[(size_t)(sbp*PP + cl) * NN + n] = f2bf(sacc[mi][rr] + bpv);
      }
  }
}

// ---------- rnorm + in-place exp(score) + expsum partials: grid 512 ----------
__global__ __launch_bounds__(256) void rnorm_kernel(
    u16* __restrict__ wbufe, const float* __restrict__ ssqp4,
    float* __restrict__ rnormb, float* __restrict__ espart) {
  __shared__ float red[4][16];
  const int t = threadIdx.x;
  const int r = blockIdx.x * 256 + t;
  const float4 sp = *(const float4*)&ssqp4[(size_t)r * 4];
  const float ss = sp.x + sp.y + sp.z + sp.w;
  const float rn = 1.f / fmaxf(sqrtf(ss), 1e-12f);
  rnormb[r] = rn;
  const int sbp = r >> 15, n = r & (NN - 1);
  float es[16];
  #pragma unroll
  for (int p = 0; p < PP; ++p) {
    u16* cell = wbufe + (size_t)(sbp*PP + p) * NN + n;
    float w = bf2f(*cell) * rn * SCALE_INV_SQRT_D;
    float e = expf(w);                 // |w| <= 0.0442 -> no max-subtract needed
    *cell = f2bf(e);
    es[p] = e;
  }
  const int lane = t & 63, wv = t >> 6;
  #pragma unroll
  for (int p = 0; p < PP; ++p) {
    float v = es[p];
    v += __shfl_xor(v, 1);  v += __shfl_xor(v, 2);  v += __shfl_xor(v, 4);
    v += __shfl_xor(v, 8);  v += __shfl_xor(v, 16); v += __shfl_xor(v, 32);
    if (lane == 0) red[wv][p] = v;
  }
  __syncthreads();
  if (t < PP) espart[(size_t)blockIdx.x * PP + t] = red[0][t] + red[1][t] + red[2][t] + red[3][t];
}

// ---------- reduce expsum partials -> iSrow[(s*2+b)*16+p]: grid 64 ----------
__global__ __launch_bounds__(256) void isum_kernel(const float* __restrict__ espart,
                                                   float* __restrict__ iSrow) {
  __shared__ float sred[4];
  const int bid = blockIdx.x, sbp = bid >> 4, p = bid & 15;
  const int t = threadIdx.x;
  float s = 0.f;
  if (t < 128) s = espart[(size_t)(sbp*128 + t)*PP + p];
  s = block_reduce_sum_256(s, sred);
  if (t == 0) iSrow[bid] = 1.f / s;
}

// ---------- attended (fused wsum): part[b][cid][d]; per-side launch ----------
__global__ __launch_bounds__(256) void attended_kernel(
    const u16* __restrict__ proj, const u16* __restrict__ wbufe,
    const float* __restrict__ rnormb, const float* __restrict__ iSrow,
    float* __restrict__ part) {
  __shared__ float wl[CHUNK];
  __shared__ float iSl[PP];
  const int b = blockIdx.y, cid = blockIdx.x, t = threadIdx.x;
  const int nbase = cid * CHUNK;
  if (t < PP) iSl[t] = iSrow[b*PP + t];
  __syncthreads();
  if (t < CHUNK) {
    const int n = nbase + t;
    float s = 0.f;
    #pragma unroll
    for (int p = 0; p < PP; ++p)
      s += bf2f(wbufe[(size_t)(b*PP + p)*NN + n]) * iSl[p];
    wl[t] = s * rnormb[b*NN + n] * (1.f / PP);
  }
  __syncthreads();
  float a0 = 0.f, a1 = 0.f;
  const u16* pb = proj + (size_t)(b*NN + nbase) * DD + 2*t;
  #pragma unroll 8
  for (int n = 0; n < CHUNK; ++n) {
    unsigned uu = *(const unsigned*)(pb + (size_t)n * DD);
    float w = wl[n];
    a0 += w * bf2f((u16)uu);
    a1 += w * bf2f((u16)(uu >> 16));
  }
  *(float2*)&part[((size_t)(b*NCHUNK + cid))*DD + 2*t] = make_float2(a0, a1);
}

// ---------- reduce chunks -> featraw[b][d]: grid (4 dchunks, 2 b) ----------
__global__ __launch_bounds__(256) void featred_kernel(
    const float* __restrict__ part, float* __restrict__ featraw) {
  __shared__ float red[2][128];
  const int b = blockIdx.y, d0 = blockIdx.x * 128, t = threadIdx.x;
  const int dl = t & 127, half = t >> 7;
  float s = 0.f;
  for (int c = half*128; c < half*128 + 128; ++c)
    s += part[((size_t)(b*NCHUNK + c))*DD + d0 + dl];
  red[half][dl] = s;
  __syncthreads();
  if (t < 128) featraw[b*DD + d0 + t] = red[0][t] + red[1][t];
}

// ---------- final: normalize feats, logits, softmax, argmax, loss ----------
__global__ __launch_bounds__(256) void final_kernel(
    const float* __restrict__ frawL, const float* __restrict__ frawH,
    const float* __restrict__ textL, const float* __restrict__ textH,
    const int* __restrict__ label, float* __restrict__ out) {
  __shared__ float sred[4];
  const int t = threadIdx.x;
  float invL[2], invH[2];
  #pragma unroll
  for (int b = 0; b < 2; ++b) {
    float v = 0.f;
    for (int d = t; d < DD; d += 256) { float x = frawL[b*DD + d]; v += x*x; }
    float ss = block_reduce_sum_256(v, sred);
    invL[b] = 1.f / fmaxf(sqrtf(ss), 1e-12f);
    v = 0.f;
    for (int d = t; d < DD; d += 256) { float x = frawH[b*DD + d]; v += x*x; }
    ss = block_reduce_sum_256(v, sred);
    invH[b] = 1.f / fmaxf(sqrtf(ss), 1e-12f);
  }
  float lg[2][2];
  #pragma unroll
  for (int b = 0; b < 2; ++b)
    #pragma unroll
    for (int c = 0; c < 2; ++c) {
      float v = 0.f;
      for (int d = t; d < DD; d += 256)
        v += frawL[b*DD + d] * invL[b] * textL[c*DD + d]
           + frawH[b*DD + d] * invH[b] * textH[c*DD + d];
      lg[b][c] = block_reduce_sum_256(v, sred);
    }
  if (t == 0) {
    float loss = 0.f;
    #pragma unroll
    for (int b = 0; b < 2; ++b) {
      const float m  = fmaxf(lg[b][0], lg[b][1]);
      const float lse = m + logf(expf(lg[b][0]-m) + expf(lg[b][1]-m));
      out[b*2+0] = expf(lg[b][0]-lse); out[b*2+1] = expf(lg[b][1]-lse);
      out[4+b] = (lg[b][1] > lg[b][0]) ? 1.f : 0.f;
      loss += -(lg[b][label[b]] - lse);
    }
    out[6] = loss * 0.5f;
  }
}

extern "C" void kernel_launch(void* const* d_in, const int* in_sizes, int n_in,
                              void* d_out, int out_size, void* d_ws, size_t ws_size,
                              hipStream_t stream) {
  (void)in_sizes; (void)n_in; (void)out_size; (void)ws_size;
  const float* x_s  = (const float*)d_in[0];
  const float* x_l  = (const float*)d_in[2];
  const float* Wp   = (const float*)d_in[4];
  const float* bp   = (const float*)d_in[5];
  const float* prot = (const float*)d_in[6];
  const float* tL   = (const float*)d_in[7];
  const float* tH   = (const float*)d_in[8];
  const int*   label= (const int*)d_in[9];
  float* out = (float*)d_out;

  unsigned char* w8 = (unsigned char*)d_ws;
  u16*   proj   = (u16*)  (w8);                  // 134,217,728 (both sides)
  u16*   wbufe  = (u16*)  (w8 + 134217728);      //   4,194,304 (scores->exp, bf16) [4][16][NN]
  float* ssqp4  = (float*)(w8 + 138412032);      //   2,097,152 (aliased by part later)
  float* part   = (float*)(w8 + 138412032);      //   1,048,576 (alias: ssqp4 dead by then)
  float* rnormb = (float*)(w8 + 140509184);      //     524,288
  float* espart = (float*)(w8 + 141033472);      //      32,768
  float* iSrow  = (float*)(w8 + 141066240);      //       1,024
  float* pn     = (float*)(w8 + 141067264);      //      32,768
  uint4* Bf     = (uint4*)(w8 + 141100032);      //     786,432
  uint4* Wpnb   = (uint4*)(w8 + 141886464);      //      24,576
  float* bpn    = (float*)(w8 + 141911040);      //       1,024
  float* frawL  = (float*)(w8 + 141912064);      //       4,096
  float* frawH  = (float*)(w8 + 141916160);      //       4,096  (end 141,920,256)

  bf_pack_kernel<<<768, 64, 0, stream>>>(Wp, Bf);
  proto_norm_kernel<<<PP, 256, 0, stream>>>(prot, pn);
  wpn_pack_kernel<<<25, 64, 0, stream>>>(Wp, pn, bp, Wpnb, bpn);

  // One GEMM dispatch over both sides (global rows 0..131071).
  gemm_kernel<<<4096, 256, 0, stream>>>(x_s, x_l, Bf, Wpnb, bp, bpn,
                                        proj, wbufe, ssqp4);
  rnorm_kernel<<<MALL/256, 256, 0, stream>>>(wbufe, ssqp4, rnormb, espart);
  isum_kernel<<<64, 256, 0, stream>>>(espart, iSrow);

  float* fts[2] = {frawL, frawH};
  for (int side = 0; side < 2; ++side) {
    attended_kernel<<<dim3(NCHUNK, BB), 256, 0, stream>>>(
        proj + (size_t)side * MTOT * DD,
        wbufe + (size_t)side * 2 * PP * NN,
        rnormb + (size_t)side * MTOT,
        iSrow + side * 32, part);
    featred_kernel<<<dim3(4, BB), 256, 0, stream>>>(part, fts[side]);
  }
  final_kernel<<<1, 256, 0, stream>>>(frawL, frawH, tL, tH, label, out);
}

// Round 8
// 358.520 us; speedup vs baseline: 1.2258x; 1.2258x over previous
//
#include <hip/hip_runtime.h>
#include <math.h>

#define BB   2
#define NN   32768
#define DIN  768
#define DD   512
#define PP   16
#define MTOT (BB*NN)          // rows per side
#define MALL (2*MTOT)         // both sides
#define NCHUNK 256
#define CHUNK  (NN/NCHUNK)    // 128
#define SCALE_INV_SQRT_D 0.04419417382415922f  // 1/sqrt(512)

typedef unsigned short u16;
typedef __attribute__((ext_vector_type(8))) short bf16x8;
typedef __attribute__((ext_vector_type(4))) float f32x4;

#define MFMA(a,b,c) __builtin_amdgcn_mfma_f32_16x16x32_bf16((a),(b),(c),0,0,0)

__device__ __forceinline__ unsigned pack2bf(float a, float b) {
  union { float f; unsigned u; } x{a}, y{b};
  unsigned ra = (x.u + 0x7FFFu + ((x.u >> 16) & 1u)) >> 16;
  unsigned rb = (y.u + 0x7FFFu + ((y.u >> 16) & 1u)) >> 16;
  return ra | (rb << 16);
}
__device__ __forceinline__ u16 f2bf(float a) {
  union { float f; unsigned u; } x{a};
  return (u16)((x.u + 0x7FFFu + ((x.u >> 16) & 1u)) >> 16);
}
__device__ __forceinline__ float bf2f(u16 u) {
  union { unsigned u; float f; } x; x.u = ((unsigned)u) << 16; return x.f;
}

__device__ __forceinline__ float block_reduce_sum_256(float v, float* sred) {
  #pragma unroll
  for (int off = 32; off; off >>= 1) v += __shfl_down(v, off);
  const int lane = threadIdx.x & 63, w = threadIdx.x >> 6;
  if (lane == 0) sred[w] = v;
  __syncthreads();
  float r = sred[0] + sred[1] + sred[2] + sred[3];
  __syncthreads();
  return r;
}

// ---------- W[768][512] fp32 -> Bf fragment layout: Bf[nf*24+ks][lane] ----------
// element: n = nf*16 + (lane&15), k = ks*32 + (lane>>4)*8 + j
__global__ __launch_bounds__(64) void bf_pack_kernel(const float* __restrict__ W,
                                                     uint4* __restrict__ Bf) {
  const int bid = blockIdx.x;            // nf*24 + ks, 768 blocks
  const int nf = bid / 24, ks = bid % 24;
  const int lane = threadIdx.x;
  const int n = nf*16 + (lane & 15);
  const int kb = ks*32 + (lane >> 4)*8;
  unsigned r0 = pack2bf(W[(size_t)(kb+0)*DD + n], W[(size_t)(kb+1)*DD + n]);
  unsigned r1 = pack2bf(W[(size_t)(kb+2)*DD + n], W[(size_t)(kb+3)*DD + n]);
  unsigned r2 = pack2bf(W[(size_t)(kb+4)*DD + n], W[(size_t)(kb+5)*DD + n]);
  unsigned r3 = pack2bf(W[(size_t)(kb+6)*DD + n], W[(size_t)(kb+7)*DD + n]);
  Bf[(size_t)bid*64 + lane] = make_uint4(r0, r1, r2, r3);
}

// ---------- normalize prototypes -> pn fp32 [16][512] ----------
__global__ __launch_bounds__(256) void proto_norm_kernel(
    const float* __restrict__ prot, float* __restrict__ pn) {
  __shared__ float sred[4];
  const int p = blockIdx.x, t = threadIdx.x;
  float2 v = *(const float2*)&prot[p*DD + 2*t];
  float ss = block_reduce_sum_256(v.x*v.x + v.y*v.y, sred);
  float sc = 1.f / fmaxf(sqrtf(ss), 1e-12f);
  *(float2*)&pn[p*DD + 2*t] = make_float2(v.x*sc, v.y*sc);
}

// ---------- Wpn = W·pn^T in B-fragment layout (p as n, 16 wide), + bpn ----------
__global__ __launch_bounds__(64) void wpn_pack_kernel(
    const float* __restrict__ W, const float* __restrict__ pn,
    const float* __restrict__ bias, uint4* __restrict__ Wpnb,
    float* __restrict__ bpn) {
  const int ks = blockIdx.x, lane = threadIdx.x;
  const int p = lane & 15;
  if (ks < 24) {
    float v[8];
    #pragma unroll
    for (int j = 0; j < 8; ++j) {
      const int k = ks*32 + (lane >> 4)*8 + j;
      const float* wr = W + (size_t)k * DD;
      const float* pr = pn + p * DD;
      float s = 0.f;
      for (int d = 0; d < DD; d += 4) {
        float4 a = *(const float4*)(wr + d);
        float4 b = *(const float4*)(pr + d);
        s += a.x*b.x + a.y*b.y + a.z*b.z + a.w*b.w;
      }
      v[j] = s;
    }
    Wpnb[ks*64 + lane] = make_uint4(pack2bf(v[0],v[1]), pack2bf(v[2],v[3]),
                                    pack2bf(v[4],v[5]), pack2bf(v[6],v[7]));
  } else {
    const int seg = lane >> 4;
    float s = 0.f;
    for (int d = seg*128; d < seg*128 + 128; ++d) s += bias[d] * pn[p*DD + d];
    s += __shfl_xor(s, 16);
    s += __shfl_xor(s, 32);
    if (lane < 16) bpn[lane] = s;
  }
}

// ---------- GEMM (round-3 structure, merged sides) + fused score/rnorm/exp ----------
// grid 2048 (64-row slabs over both sides), 256 threads = 4 waves, wave 64x128.
// BM=64, BN=512 (A read once), BK=64. B register-direct from L2-resident Bf.
// 1 barrier per kt. Epilogue: proj bf16, rnorm, exp(score), expsum partials.
__global__ __launch_bounds__(256, 2) void gemm_kernel(
    const float* __restrict__ Xs, const float* __restrict__ Xl,
    const uint4* __restrict__ Bf, const uint4* __restrict__ Wpnb,
    const float* __restrict__ bias, const float* __restrict__ bpn,
    u16* __restrict__ proj, u16* __restrict__ wbufe,
    float* __restrict__ rnormb, float* __restrict__ espart) {
  __shared__ __align__(16) unsigned char Alds[2][8192];
  __shared__ float ssqred[64][4];
  __shared__ float rnl[64];
  const int t = threadIdx.x, lane = t & 63, wn = t >> 6;
  const int cl = lane & 15, cg = lane >> 4;
  const int m0g = blockIdx.x * 64;             // global row over both sides
  const float* Xb = (m0g < MTOT) ? Xs : Xl;    // 65536 % 64 == 0: no straddle
  const int m0l = m0g & (MTOT - 1);
  // A staging (round-3 wslot): thread covers row r, k's {c4*4+q*16+i}
  const int r = t >> 2, c4 = t & 3;
  const float* gA = Xb + (size_t)(m0l + r) * DIN + c4 * 4;
  int wslot[4];
  #pragma unroll
  for (int q = 0; q < 4; ++q)
    wslot[q] = (((r>>4)*2 + (q>>1))*64 + ((q&1)*2 + (c4>>1))*16 + (r&15)) * 16 + (c4&1)*8;

  const bool do_score = (wn == 0);
  f32x4 acc[4][8] = {};
  f32x4 sacc[4] = {};
  float4 va[4];
  #pragma unroll
  for (int q = 0; q < 4; ++q) va[q] = *(const float4*)(gA + q*16);
  #pragma unroll
  for (int q = 0; q < 4; ++q)
    *(uint2*)(&Alds[0][wslot[q]]) =
        make_uint2(pack2bf(va[q].x, va[q].y), pack2bf(va[q].z, va[q].w));

  for (int kt = 0; kt < 12; ++kt) {
    const int cur = kt & 1;
    if (kt < 11) {
      #pragma unroll
      for (int q = 0; q < 4; ++q) va[q] = *(const float4*)(gA + (kt+1)*64 + q*16);
    }
    bf16x8 b0[8];
    #pragma unroll
    for (int j = 0; j < 8; ++j)
      b0[j] = *(const bf16x8*)(Bf + (size_t)((wn*8 + j)*24 + kt*2) * 64 + lane);
    __syncthreads();
    bf16x8 af0[4], af1[4];
    #pragma unroll
    for (int m = 0; m < 4; ++m)
      af0[m] = *(const bf16x8*)(&Alds[cur][((m*2 + 0)*64 + lane)*16]);
    #pragma unroll
    for (int m = 0; m < 4; ++m)
      af1[m] = *(const bf16x8*)(&Alds[cur][((m*2 + 1)*64 + lane)*16]);
    #pragma unroll
    for (int j = 0; j < 8; ++j)
      #pragma unroll
      for (int m = 0; m < 4; ++m)
        acc[m][j] = MFMA(af0[m], b0[j], acc[m][j]);
    bf16x8 b1[8];
    #pragma unroll
    for (int j = 0; j < 8; ++j)
      b1[j] = *(const bf16x8*)(Bf + (size_t)((wn*8 + j)*24 + kt*2 + 1) * 64 + lane);
    #pragma unroll
    for (int j = 0; j < 8; ++j)
      #pragma unroll
      for (int m = 0; m < 4; ++m)
        acc[m][j] = MFMA(af1[m], b1[j], acc[m][j]);
    if (do_score) {
      bf16x8 wf0 = *(const bf16x8*)(Wpnb + (kt*2)*64 + lane);
      bf16x8 wf1 = *(const bf16x8*)(Wpnb + (kt*2 + 1)*64 + lane);
      #pragma unroll
      for (int m = 0; m < 4; ++m) {
        sacc[m] = MFMA(af0[m], wf0, sacc[m]);
        sacc[m] = MFMA(af1[m], wf1, sacc[m]);
      }
    }
    if (kt < 11) {
      #pragma unroll
      for (int q = 0; q < 4; ++q)
        *(uint2*)(&Alds[cur^1][wslot[q]]) =
            make_uint2(pack2bf(va[q].x, va[q].y), pack2bf(va[q].z, va[q].w));
    }
  }
  // ---- epilogue: bias, proj store, ssq -> rnorm, scores -> exp + partials
  float bv[8];
  #pragma unroll
  for (int j = 0; j < 8; ++j) bv[j] = bias[wn*128 + j*16 + cl];
  #pragma unroll
  for (int m = 0; m < 4; ++m) {
    #pragma unroll
    for (int rr = 0; rr < 4; ++rr) {
      const int rowl = m*16 + cg*4 + rr;
      u16* pr = proj + (size_t)(m0g + rowl) * DD + wn*128 + cl;
      float sq = 0.f;
      #pragma unroll
      for (int j = 0; j < 8; ++j) {
        float val = acc[m][j][rr] + bv[j];
        pr[j*16] = f2bf(val);
        sq += val * val;
      }
      sq += __shfl_xor(sq, 1); sq += __shfl_xor(sq, 2);
      sq += __shfl_xor(sq, 4); sq += __shfl_xor(sq, 8);
      if (cl == 0) ssqred[rowl][wn] = sq;
    }
  }
  __syncthreads();
  if (t < 64) {
    float ss = ssqred[t][0] + ssqred[t][1] + ssqred[t][2] + ssqred[t][3];
    float rn = 1.f / fmaxf(sqrtf(ss), 1e-12f);
    rnl[t] = rn;
    rnormb[m0g + t] = rn;
  }
  __syncthreads();
  if (do_score) {
    const float bpv = bpn[cl];
    float esum = 0.f;
    #pragma unroll
    for (int m = 0; m < 4; ++m)
      #pragma unroll
      for (int rr = 0; rr < 4; ++rr) {
        const int rowl = m*16 + cg*4 + rr;
        const float sc = (sacc[m][rr] + bpv) * rnl[rowl] * SCALE_INV_SQRT_D;
        const float e = expf(sc);        // |sc| <= ~0.0442: no max-subtract needed
        esum += e;
        const int grow = m0g + rowl;
        const int sbp = grow >> 15, n = grow & (NN - 1);   // sbp = side*2+b
        wbufe[(size_t)(sbp*PP + cl) * NN + n] = f2bf(e);
      }
    esum += __shfl_xor(esum, 16);
    esum += __shfl_xor(esum, 32);
    if (cg == 0) espart[(size_t)blockIdx.x * PP + cl] = esum;
  }
}

// ---------- reduce expsum partials -> iSrow[(side*2+b)*16+p]: grid 64 ----------
__global__ __launch_bounds__(256) void isum_kernel(const float* __restrict__ espart,
                                                   float* __restrict__ iSrow) {
  __shared__ float sred[4];
  const int bid = blockIdx.x, sbp = bid >> 4, p = bid & 15;
  const int t = threadIdx.x;
  float s = espart[(size_t)(sbp*512 + t)*PP + p]
          + espart[(size_t)(sbp*512 + 256 + t)*PP + p];
  s = block_reduce_sum_256(s, sred);
  if (t == 0) iSrow[bid] = 1.f / s;
}

// ---------- attended (fused wsum): part[b][cid][d]; per-side launch ----------
__global__ __launch_bounds__(256) void attended_kernel(
    const u16* __restrict__ proj, const u16* __restrict__ wbufe,
    const float* __restrict__ rnormb, const float* __restrict__ iSrow,
    float* __restrict__ part) {
  __shared__ float wl[CHUNK];
  __shared__ float iSl[PP];
  const int b = blockIdx.y, cid = blockIdx.x, t = threadIdx.x;
  const int nbase = cid * CHUNK;
  if (t < PP) iSl[t] = iSrow[b*PP + t];
  __syncthreads();
  if (t < CHUNK) {
    const int n = nbase + t;
    float s = 0.f;
    #pragma unroll
    for (int p = 0; p < PP; ++p)
      s += bf2f(wbufe[(size_t)(b*PP + p)*NN + n]) * iSl[p];
    wl[t] = s * rnormb[b*NN + n] * (1.f / PP);
  }
  __syncthreads();
  float a0 = 0.f, a1 = 0.f;
  const u16* pb = proj + (size_t)(b*NN + nbase) * DD + 2*t;
  #pragma unroll 8
  for (int n = 0; n < CHUNK; ++n) {
    unsigned uu = *(const unsigned*)(pb + (size_t)n * DD);
    float w = wl[n];
    a0 += w * bf2f((u16)uu);
    a1 += w * bf2f((u16)(uu >> 16));
  }
  *(float2*)&part[((size_t)(b*NCHUNK + cid))*DD + 2*t] = make_float2(a0, a1);
}

// ---------- reduce chunks -> featraw[b][d]: grid (4 dchunks, 2 b) ----------
__global__ __launch_bounds__(256) void featred_kernel(
    const float* __restrict__ part, float* __restrict__ featraw) {
  __shared__ float red[2][128];
  const int b = blockIdx.y, d0 = blockIdx.x * 128, t = threadIdx.x;
  const int dl = t & 127, half = t >> 7;
  float s = 0.f;
  for (int c = half*128; c < half*128 + 128; ++c)
    s += part[((size_t)(b*NCHUNK + c))*DD + d0 + dl];
  red[half][dl] = s;
  __syncthreads();
  if (t < 128) featraw[b*DD + d0 + t] = red[0][t] + red[1][t];
}

// ---------- final: normalize feats, logits, softmax, argmax, loss ----------
__global__ __launch_bounds__(256) void final_kernel(
    const float* __restrict__ frawL, const float* __restrict__ frawH,
    const float* __restrict__ textL, const float* __restrict__ textH,
    const int* __restrict__ label, float* __restrict__ out) {
  __shared__ float sred[4];
  const int t = threadIdx.x;
  float invL[2], invH[2];
  #pragma unroll
  for (int b = 0; b < 2; ++b) {
    float v = 0.f;
    for (int d = t; d < DD; d += 256) { float x = frawL[b*DD + d]; v += x*x; }
    float ss = block_reduce_sum_256(v, sred);
    invL[b] = 1.f / fmaxf(sqrtf(ss), 1e-12f);
    v = 0.f;
    for (int d = t; d < DD; d += 256) { float x = frawH[b*DD + d]; v += x*x; }
    ss = block_reduce_sum_256(v, sred);
    invH[b] = 1.f / fmaxf(sqrtf(ss), 1e-12f);
  }
  float lg[2][2];
  #pragma unroll
  for (int b = 0; b < 2; ++b)
    #pragma unroll
    for (int c = 0; c < 2; ++c) {
      float v = 0.f;
      for (int d = t; d < DD; d += 256)
        v += frawL[b*DD + d] * invL[b] * textL[c*DD + d]
           + frawH[b*DD + d] * invH[b] * textH[c*DD + d];
      lg[b][c] = block_reduce_sum_256(v, sred);
    }
  if (t == 0) {
    float loss = 0.f;
    #pragma unroll
    for (int b = 0; b < 2; ++b) {
      const float m  = fmaxf(lg[b][0], lg[b][1]);
      const float lse = m + logf(expf(lg[b][0]-m) + expf(lg[b][1]-m));
      out[b*2+0] = expf(lg[b][0]-lse); out[b*2+1] = expf(lg[b][1]-lse);
      out[4+b] = (lg[b][1] > lg[b][0]) ? 1.f : 0.f;
      loss += -(lg[b][label[b]] - lse);
    }
    out[6] = loss * 0.5f;
  }
}

extern "C" void kernel_launch(void* const* d_in, const int* in_sizes, int n_in,
                              void* d_out, int out_size, void* d_ws, size_t ws_size,
                              hipStream_t stream) {
  (void)in_sizes; (void)n_in; (void)out_size; (void)ws_size;
  const float* x_s  = (const float*)d_in[0];
  const float* x_l  = (const float*)d_in[2];
  const float* Wp   = (const float*)d_in[4];
  const float* bp   = (const float*)d_in[5];
  const float* prot = (const float*)d_in[6];
  const float* tL   = (const float*)d_in[7];
  const float* tH   = (const float*)d_in[8];
  const int*   label= (const int*)d_in[9];
  float* out = (float*)d_out;

  unsigned char* w8 = (unsigned char*)d_ws;
  u16*   proj   = (u16*)  (w8);                  // 134,217,728 (both sides)
  u16*   wbufe  = (u16*)  (w8 + 134217728);      //   4,194,304  exp(score) bf16 [4][16][NN]
  float* part   = (float*)(w8 + 138412032);      //   1,048,576
  float* rnormb = (float*)(w8 + 139460608);      //     524,288
  float* espart = (float*)(w8 + 139984896);      //     131,072  [2048][16]
  float* iSrow  = (float*)(w8 + 140115968);      //       1,024
  float* pn     = (float*)(w8 + 140116992);      //      32,768
  uint4* Bf     = (uint4*)(w8 + 140149760);      //     786,432
  uint4* Wpnb   = (uint4*)(w8 + 140936192);      //      24,576
  float* bpn    = (float*)(w8 + 140960768);      //       1,024
  float* frawL  = (float*)(w8 + 140961792);      //       4,096
  float* frawH  = (float*)(w8 + 140965888);      //       4,096  (end 140,969,984)

  bf_pack_kernel<<<768, 64, 0, stream>>>(Wp, Bf);
  proto_norm_kernel<<<PP, 256, 0, stream>>>(prot, pn);
  wpn_pack_kernel<<<25, 64, 0, stream>>>(Wp, pn, bp, Wpnb, bpn);

  gemm_kernel<<<MALL/64, 256, 0, stream>>>(x_s, x_l, Bf, Wpnb, bp, bpn,
                                           proj, wbufe, rnormb, espart);
  isum_kernel<<<64, 256, 0, stream>>>(espart, iSrow);

  float* fts[2] = {frawL, frawH};
  for (int side = 0; side < 2; ++side) {
    attended_kernel<<<dim3(NCHUNK, BB), 256, 0, stream>>>(
        proj + (size_t)side * MTOT * DD,
        wbufe + (size_t)side * 2 * PP * NN,
        rnormb + (size_t)side * MTOT,
        iSrow + side * 32, part);
    featred_kernel<<<dim3(4, BB), 256, 0, stream>>>(part, fts[side]);
  }
  final_kernel<<<1, 256, 0, stream>>>(frawL, frawH, tL, tH, label, out);
}

// Round 9
// 304.025 us; speedup vs baseline: 1.4455x; 1.1792x over previous
//
#include <hip/hip_runtime.h>
#include <math.h>

#define BB   2
#define NN   32768
#define DIN  768
#define DD   512
#define PP   16
#define MTOT (BB*NN)          // rows per side
#define MALL (2*MTOT)         // both sides
#define NCHUNK 128
#define CHUNK  (NN/NCHUNK)    // 256
#define SCALE_INV_SQRT_D 0.04419417382415922f  // 1/sqrt(512)

typedef unsigned short u16;
typedef __attribute__((ext_vector_type(8))) short bf16x8;
typedef __attribute__((ext_vector_type(4))) float f32x4;

#define MFMA(a,b,c) __builtin_amdgcn_mfma_f32_16x16x32_bf16((a),(b),(c),0,0,0)

__device__ __forceinline__ unsigned pack2bf(float a, float b) {
  union { float f; unsigned u; } x{a}, y{b};
  unsigned ra = (x.u + 0x7FFFu + ((x.u >> 16) & 1u)) >> 16;
  unsigned rb = (y.u + 0x7FFFu + ((y.u >> 16) & 1u)) >> 16;
  return ra | (rb << 16);
}
__device__ __forceinline__ u16 f2bf(float a) {
  union { float f; unsigned u; } x{a};
  return (u16)((x.u + 0x7FFFu + ((x.u >> 16) & 1u)) >> 16);
}
__device__ __forceinline__ float bf2f(u16 u) {
  union { unsigned u; float f; } x; x.u = ((unsigned)u) << 16; return x.f;
}

__device__ __forceinline__ float block_reduce_sum_256(float v, float* sred) {
  #pragma unroll
  for (int off = 32; off; off >>= 1) v += __shfl_down(v, off);
  const int lane = threadIdx.x & 63, w = threadIdx.x >> 6;
  if (lane == 0) sred[w] = v;
  __syncthreads();
  float r = sred[0] + sred[1] + sred[2] + sred[3];
  __syncthreads();
  return r;
}

// ---------- merged prepass: bf_pack (bid<768) | Wpn+bpn with inline proto-norm ----------
__global__ __launch_bounds__(64) void pre_kernel(
    const float* __restrict__ W, const float* __restrict__ prot,
    const float* __restrict__ bias, uint4* __restrict__ Bf,
    uint4* __restrict__ Wpnb, float* __restrict__ bpn) {
  const int bid = blockIdx.x;
  const int lane = threadIdx.x;
  if (bid < 768) {
    // Bf[nf*24+ks][lane]: n = nf*16 + (lane&15), k = ks*32 + (lane>>4)*8 + j
    const int nf = bid / 24, ks = bid % 24;
    const int n = nf*16 + (lane & 15);
    const int kb = ks*32 + (lane >> 4)*8;
    unsigned r0 = pack2bf(W[(size_t)(kb+0)*DD + n], W[(size_t)(kb+1)*DD + n]);
    unsigned r1 = pack2bf(W[(size_t)(kb+2)*DD + n], W[(size_t)(kb+3)*DD + n]);
    unsigned r2 = pack2bf(W[(size_t)(kb+4)*DD + n], W[(size_t)(kb+5)*DD + n]);
    unsigned r3 = pack2bf(W[(size_t)(kb+6)*DD + n], W[(size_t)(kb+7)*DD + n]);
    Bf[(size_t)bid*64 + lane] = make_uint4(r0, r1, r2, r3);
    return;
  }
  const int ks = bid - 768;          // 0..24
  const int p = lane & 15, seg = lane >> 4;
  // inline prototype L2 norm (lanes p,p+16,p+32,p+48 cooperate)
  float ssq = 0.f;
  for (int d = seg*128; d < seg*128 + 128; d += 4) {
    float4 v = *(const float4*)&prot[p*DD + d];
    ssq += v.x*v.x + v.y*v.y + v.z*v.z + v.w*v.w;
  }
  ssq += __shfl_xor(ssq, 16);
  ssq += __shfl_xor(ssq, 32);
  const float rnp = 1.f / fmaxf(sqrtf(ssq), 1e-12f);
  if (ks < 24) {
    float v[8];
    #pragma unroll
    for (int j = 0; j < 8; ++j) {
      const int k = ks*32 + seg*8 + j;
      const float* wr = W + (size_t)k * DD;
      const float* pr = prot + p * DD;
      float s = 0.f;
      for (int d = 0; d < DD; d += 4) {
        float4 a = *(const float4*)(wr + d);
        float4 b = *(const float4*)(pr + d);
        s += a.x*b.x + a.y*b.y + a.z*b.z + a.w*b.w;
      }
      v[j] = s * rnp;
    }
    Wpnb[ks*64 + lane] = make_uint4(pack2bf(v[0],v[1]), pack2bf(v[2],v[3]),
                                    pack2bf(v[4],v[5]), pack2bf(v[6],v[7]));
  } else {
    float s = 0.f;
    for (int d = seg*128; d < seg*128 + 128; ++d) s += bias[d] * prot[p*DD + d];
    s += __shfl_xor(s, 16);
    s += __shfl_xor(s, 32);
    if (lane < 16) bpn[lane] = s * rnp;
  }
}

// ---------- GEMM + fused score/rnorm/exp, software-pipelined B issue ----------
// grid 2048 (64-row slabs over both sides), 256 thr = 4 waves, wave 64x128.
// BM=64, BN=512 (A read once), BK=64. B register-direct from L2-resident Bf,
// issued in 4-frag groups one group ahead of consumption.
__global__ __launch_bounds__(256, 2) void gemm_kernel(
    const float* __restrict__ Xs, const float* __restrict__ Xl,
    const uint4* __restrict__ Bf, const uint4* __restrict__ Wpnb,
    const float* __restrict__ bias, const float* __restrict__ bpn,
    u16* __restrict__ proj, u16* __restrict__ wbufe,
    float* __restrict__ rnormb, float* __restrict__ espart) {
  __shared__ __align__(16) unsigned char Alds[2][8192];
  __shared__ float ssqred[64][4];
  __shared__ float rnl[64];
  __shared__ u16 sbuf[16][64];
  const int t = threadIdx.x, lane = t & 63, wn = t >> 6;
  const int cl = lane & 15, cg = lane >> 4;
  const int m0g = blockIdx.x * 64;             // global row over both sides
  const float* Xb = (m0g < MTOT) ? Xs : Xl;    // 65536 % 64 == 0: no straddle
  const int m0l = m0g & (MTOT - 1);
  // A staging (proven wslot): thread covers row r, k's {c4*4 + q*16 + i}
  const int r = t >> 2, c4 = t & 3;
  const float* gA = Xb + (size_t)(m0l + r) * DIN + c4 * 4;
  int wslot[4];
  #pragma unroll
  for (int q = 0; q < 4; ++q)
    wslot[q] = (((r>>4)*2 + (q>>1))*64 + ((q&1)*2 + (c4>>1))*16 + (r&15)) * 16 + (c4&1)*8;

  const bool do_score = (wn == 0);
  f32x4 acc[4][8] = {};
  f32x4 sacc[4] = {};

#define LDB(dst, jj, ksx) \
  dst = *(const bf16x8*)(Bf + (size_t)((wn*8 + (jj))*24 + (ksx)) * 64 + lane)
#define MFMA4(afr, barr, jb) \
  { _Pragma("unroll") \
    for (int j_ = 0; j_ < 4; ++j_) { \
      _Pragma("unroll") \
      for (int m_ = 0; m_ < 4; ++m_) \
        acc[m_][(jb)+j_] = MFMA(afr[m_], barr[j_], acc[m_][(jb)+j_]); \
    } }

  {
    float4 va[4];
    #pragma unroll
    for (int q = 0; q < 4; ++q) va[q] = *(const float4*)(gA + q*16);
    #pragma unroll
    for (int q = 0; q < 4; ++q)
      *(uint2*)(&Alds[0][wslot[q]]) =
          make_uint2(pack2bf(va[q].x, va[q].y), pack2bf(va[q].z, va[q].w));
  }
  bf16x8 bP[4], bQ[4];
  #pragma unroll
  for (int j = 0; j < 4; ++j) LDB(bP[j], j, 0);   // G0 of kt=0

  for (int kt = 0; kt < 12; ++kt) {
    const int cur = kt & 1, ks0 = kt*2, ks1 = kt*2 + 1;
    float4 va[4];
    if (kt < 11) {
      #pragma unroll
      for (int q = 0; q < 4; ++q) va[q] = *(const float4*)(gA + (kt+1)*64 + q*16);
    }
    __syncthreads();
    bf16x8 af0[4], af1[4];
    #pragma unroll
    for (int m = 0; m < 4; ++m)
      af0[m] = *(const bf16x8*)(&Alds[cur][((m*2 + 0)*64 + lane)*16]);
    #pragma unroll
    for (int m = 0; m < 4; ++m)
      af1[m] = *(const bf16x8*)(&Alds[cur][((m*2 + 1)*64 + lane)*16]);
    // G1 issue, G0 compute
    #pragma unroll
    for (int j = 0; j < 4; ++j) LDB(bQ[j], 4+j, ks0);
    __builtin_amdgcn_s_setprio(1);
    MFMA4(af0, bP, 0);
    __builtin_amdgcn_s_setprio(0);
    // G2 issue, G1 compute
    #pragma unroll
    for (int j = 0; j < 4; ++j) LDB(bP[j], j, ks1);
    __builtin_amdgcn_s_setprio(1);
    MFMA4(af0, bQ, 4);
    __builtin_amdgcn_s_setprio(0);
    // G3 issue (+ Wpn), G2 compute
    #pragma unroll
    for (int j = 0; j < 4; ++j) LDB(bQ[j], 4+j, ks1);
    bf16x8 wf0, wf1;
    if (do_score) {
      wf0 = *(const bf16x8*)(Wpnb + ks0*64 + lane);
      wf1 = *(const bf16x8*)(Wpnb + ks1*64 + lane);
    }
    __builtin_amdgcn_s_setprio(1);
    MFMA4(af1, bP, 0);
    __builtin_amdgcn_s_setprio(0);
    // A stage for kt+1 + next G0 issue, G3 compute
    if (kt < 11) {
      #pragma unroll
      for (int q = 0; q < 4; ++q)
        *(uint2*)(&Alds[cur^1][wslot[q]]) =
            make_uint2(pack2bf(va[q].x, va[q].y), pack2bf(va[q].z, va[q].w));
      #pragma unroll
      for (int j = 0; j < 4; ++j) LDB(bP[j], j, ks0 + 2);
    }
    __builtin_amdgcn_s_setprio(1);
    MFMA4(af1, bQ, 4);
    if (do_score) {
      #pragma unroll
      for (int m = 0; m < 4; ++m) {
        sacc[m] = MFMA(af0[m], wf0, sacc[m]);
        sacc[m] = MFMA(af1[m], wf1, sacc[m]);
      }
    }
    __builtin_amdgcn_s_setprio(0);
  }
#undef LDB
#undef MFMA4
  // ---- epilogue: bias, proj store, ssq -> rnorm, scores -> exp + partials
  float bv[8];
  #pragma unroll
  for (int j = 0; j < 8; ++j) bv[j] = bias[wn*128 + j*16 + cl];
  #pragma unroll
  for (int m = 0; m < 4; ++m) {
    #pragma unroll
    for (int rr = 0; rr < 4; ++rr) {
      const int rowl = m*16 + cg*4 + rr;
      u16* pr = proj + (size_t)(m0g + rowl) * DD + wn*128 + cl;
      float sq = 0.f;
      #pragma unroll
      for (int j = 0; j < 8; ++j) {
        float val = acc[m][j][rr] + bv[j];
        pr[j*16] = f2bf(val);
        sq += val * val;
      }
      sq += __shfl_xor(sq, 1); sq += __shfl_xor(sq, 2);
      sq += __shfl_xor(sq, 4); sq += __shfl_xor(sq, 8);
      if (cl == 0) ssqred[rowl][wn] = sq;
    }
  }
  __syncthreads();
  if (t < 64) {
    float ss = ssqred[t][0] + ssqred[t][1] + ssqred[t][2] + ssqred[t][3];
    float rn = 1.f / fmaxf(sqrtf(ss), 1e-12f);
    rnl[t] = rn;
    rnormb[m0g + t] = rn;
  }
  __syncthreads();
  if (do_score) {
    const float bpv = bpn[cl];
    float esum = 0.f;
    #pragma unroll
    for (int m = 0; m < 4; ++m)
      #pragma unroll
      for (int rr = 0; rr < 4; ++rr) {
        const int rowl = m*16 + cg*4 + rr;
        const float sc = (sacc[m][rr] + bpv) * rnl[rowl] * SCALE_INV_SQRT_D;
        const float e = expf(sc);      // |sc| <= ~0.0442: no max-subtract needed
        esum += e;
        sbuf[cl][rowl] = f2bf(e);      // stage for coalesced store
      }
    esum += __shfl_xor(esum, 16);
    esum += __shfl_xor(esum, 32);
    if (cg == 0) espart[(size_t)blockIdx.x * PP + cl] = esum;
  }
  __syncthreads();
  {  // coalesced wbufe store: 4 u16 per thread, 128B per p-row
    const int p = t >> 4, i4 = (t & 15) * 4;
    const int sbp = m0g >> 15, nb0 = m0g & (NN - 1);
    *(uint2*)&wbufe[(size_t)(sbp*PP + p) * NN + nb0 + i4] =
        *(const uint2*)&sbuf[p][i4];
  }
}

// ---------- reduce expsum partials -> iSrow[(side*2+b)*16+p]: grid 64 ----------
__global__ __launch_bounds__(256) void isum_kernel(const float* __restrict__ espart,
                                                   float* __restrict__ iSrow) {
  __shared__ float sred[4];
  const int bid = blockIdx.x, sbp = bid >> 4, p = bid & 15;
  const int t = threadIdx.x;
  float s = espart[(size_t)(sbp*512 + t)*PP + p]
          + espart[(size_t)(sbp*512 + 256 + t)*PP + p];
  s = block_reduce_sum_256(s, sred);
  if (t == 0) iSrow[bid] = 1.f / s;
}

// ---------- attended (fused wsum), both sides: grid (NCHUNK, 4) ----------
__global__ __launch_bounds__(256) void attended_kernel(
    const u16* __restrict__ proj, const u16* __restrict__ wbufe,
    const float* __restrict__ rnormb, const float* __restrict__ iSrow,
    float* __restrict__ part) {
  __shared__ float wl[CHUNK];
  __shared__ float iSl[PP];
  const int sb = blockIdx.y, cid = blockIdx.x, t = threadIdx.x;
  const int nbase = cid * CHUNK;
  if (t < PP) iSl[t] = iSrow[sb*PP + t];
  __syncthreads();
  if (t < CHUNK) {
    const int n = nbase + t;
    float s = 0.f;
    #pragma unroll
    for (int p = 0; p < PP; ++p)
      s += bf2f(wbufe[(size_t)(sb*PP + p)*NN + n]) * iSl[p];
    wl[t] = s * rnormb[sb*NN + n] * (1.f / PP);
  }
  __syncthreads();
  float a0 = 0.f, a1 = 0.f;
  const u16* pb = proj + ((size_t)sb * NN + nbase) * DD + 2*t;
  #pragma unroll 8
  for (int n = 0; n < CHUNK; ++n) {
    unsigned uu = *(const unsigned*)(pb + (size_t)n * DD);
    float w = wl[n];
    a0 += w * bf2f((u16)uu);
    a1 += w * bf2f((u16)(uu >> 16));
  }
  *(float2*)&part[((size_t)(sb*NCHUNK + cid))*DD + 2*t] = make_float2(a0, a1);
}

// ---------- reduce chunks -> fraw[sb][d]: grid (4 dchunks, 4 sb) ----------
__global__ __launch_bounds__(256) void featred_kernel(
    const float* __restrict__ part, float* __restrict__ fraw) {
  __shared__ float red[2][128];
  const int sb = blockIdx.y, d0 = blockIdx.x * 128, t = threadIdx.x;
  const int dl = t & 127, half = t >> 7;
  float s = 0.f;
  for (int c = half*64; c < half*64 + 64; ++c)
    s += part[((size_t)(sb*NCHUNK + c))*DD + d0 + dl];
  red[half][dl] = s;
  __syncthreads();
  if (t < 128) fraw[sb*DD + d0 + t] = red[0][t] + red[1][t];
}

// ---------- final: normalize feats, logits, softmax, argmax, loss ----------
__global__ __launch_bounds__(256) void final_kernel(
    const float* __restrict__ fraw, const float* __restrict__ textL,
    const float* __restrict__ textH, const int* __restrict__ label,
    float* __restrict__ out) {
  __shared__ float sred[4];
  const int t = threadIdx.x;
  const float* frawL = fraw;            // sb 0,1 = x_s b0,b1
  const float* frawH = fraw + 2*DD;     // sb 2,3 = x_l b0,b1
  float invL[2], invH[2];
  #pragma unroll
  for (int b = 0; b < 2; ++b) {
    float v = 0.f;
    for (int d = t; d < DD; d += 256) { float x = frawL[b*DD + d]; v += x*x; }
    float ss = block_reduce_sum_256(v, sred);
    invL[b] = 1.f / fmaxf(sqrtf(ss), 1e-12f);
    v = 0.f;
    for (int d = t; d < DD; d += 256) { float x = frawH[b*DD + d]; v += x*x; }
    ss = block_reduce_sum_256(v, sred);
    invH[b] = 1.f / fmaxf(sqrtf(ss), 1e-12f);
  }
  float lg[2][2];
  #pragma unroll
  for (int b = 0; b < 2; ++b)
    #pragma unroll
    for (int c = 0; c < 2; ++c) {
      float v = 0.f;
      for (int d = t; d < DD; d += 256)
        v += frawL[b*DD + d] * invL[b] * textL[c*DD + d]
           + frawH[b*DD + d] * invH[b] * textH[c*DD + d];
      lg[b][c] = block_reduce_sum_256(v, sred);
    }
  if (t == 0) {
    float loss = 0.f;
    #pragma unroll
    for (int b = 0; b < 2; ++b) {
      const float m  = fmaxf(lg[b][0], lg[b][1]);
      const float lse = m + logf(expf(lg[b][0]-m) + expf(lg[b][1]-m));
      out[b*2+0] = expf(lg[b][0]-lse); out[b*2+1] = expf(lg[b][1]-lse);
      out[4+b] = (lg[b][1] > lg[b][0]) ? 1.f : 0.f;
      loss += -(lg[b][label[b]] - lse);
    }
    out[6] = loss * 0.5f;
  }
}

extern "C" void kernel_launch(void* const* d_in, const int* in_sizes, int n_in,
                              void* d_out, int out_size, void* d_ws, size_t ws_size,
                              hipStream_t stream) {
  (void)in_sizes; (void)n_in; (void)out_size; (void)ws_size;
  const float* x_s  = (const float*)d_in[0];
  const float* x_l  = (const float*)d_in[2];
  const float* Wp   = (const float*)d_in[4];
  const float* bp   = (const float*)d_in[5];
  const float* prot = (const float*)d_in[6];
  const float* tL   = (const float*)d_in[7];
  const float* tH   = (const float*)d_in[8];
  const int*   label= (const int*)d_in[9];
  float* out = (float*)d_out;

  unsigned char* w8 = (unsigned char*)d_ws;
  u16*   proj   = (u16*)  (w8);                  // 134,217,728 (both sides)
  u16*   wbufe  = (u16*)  (w8 + 134217728);      //   4,194,304  exp(score) bf16 [4][16][NN]
  float* part   = (float*)(w8 + 138412032);      //   1,048,576  [4][NCHUNK][DD]
  float* rnormb = (float*)(w8 + 139460608);      //     524,288  [131072]
  float* espart = (float*)(w8 + 139984896);      //     131,072  [2048][16]
  float* iSrow  = (float*)(w8 + 140115968);      //       1,024
  uint4* Bf     = (uint4*)(w8 + 140116992);      //     786,432
  uint4* Wpnb   = (uint4*)(w8 + 140903424);      //      24,576
  float* bpn    = (float*)(w8 + 140928000);      //       1,024
  float* fraw   = (float*)(w8 + 140929024);      //       8,192  [4][512]

  pre_kernel<<<793, 64, 0, stream>>>(Wp, prot, bp, Bf, Wpnb, bpn);
  gemm_kernel<<<MALL/64, 256, 0, stream>>>(x_s, x_l, Bf, Wpnb, bp, bpn,
                                           proj, wbufe, rnormb, espart);
  isum_kernel<<<64, 256, 0, stream>>>(espart, iSrow);
  attended_kernel<<<dim3(NCHUNK, 4), 256, 0, stream>>>(proj, wbufe, rnormb, iSrow, part);
  featred_kernel<<<dim3(4, 4), 256, 0, stream>>>(part, fraw);
  final_kernel<<<1, 256, 0, stream>>>(fraw, tL, tH, label, out);
}

// Round 10
// 270.021 us; speedup vs baseline: 1.6275x; 1.1259x over previous
//
#include <hip/hip_runtime.h>
#include <math.h>

#define BB   2
#define NN   32768
#define DIN  768
#define DD   512
#define PP   16
#define MTOT (BB*NN)          // rows per side
#define MALL (2*MTOT)         // both sides
#define NCHUNK 128
#define CHUNK  (NN/NCHUNK)    // 256
#define SCALE_INV_SQRT_D 0.04419417382415922f  // 1/sqrt(512)

typedef unsigned short u16;
typedef __attribute__((ext_vector_type(8))) short bf16x8;
typedef __attribute__((ext_vector_type(4))) float f32x4;

#define MFMA(a,b,c) __builtin_amdgcn_mfma_f32_16x16x32_bf16((a),(b),(c),0,0,0)

__device__ __forceinline__ unsigned pack2bf(float a, float b) {
  union { float f; unsigned u; } x{a}, y{b};
  unsigned ra = (x.u + 0x7FFFu + ((x.u >> 16) & 1u)) >> 16;
  unsigned rb = (y.u + 0x7FFFu + ((y.u >> 16) & 1u)) >> 16;
  return ra | (rb << 16);
}
__device__ __forceinline__ u16 f2bf(float a) {
  union { float f; unsigned u; } x{a};
  return (u16)((x.u + 0x7FFFu + ((x.u >> 16) & 1u)) >> 16);
}
__device__ __forceinline__ float bf2f(u16 u) {
  union { unsigned u; float f; } x; x.u = ((unsigned)u) << 16; return x.f;
}

__device__ __forceinline__ float block_reduce_sum_256(float v, float* sred) {
  #pragma unroll
  for (int off = 32; off; off >>= 1) v += __shfl_down(v, off);
  const int lane = threadIdx.x & 63, w = threadIdx.x >> 6;
  if (lane == 0) sred[w] = v;
  __syncthreads();
  float r = sred[0] + sred[1] + sred[2] + sred[3];
  __syncthreads();
  return r;
}

// ---------- merged prepass: bf_pack (bid<768) | Wpn+bpn with inline proto-norm ----------
__global__ __launch_bounds__(64) void pre_kernel(
    const float* __restrict__ W, const float* __restrict__ prot,
    const float* __restrict__ bias, uint4* __restrict__ Bf,
    uint4* __restrict__ Wpnb, float* __restrict__ bpn) {
  const int bid = blockIdx.x;
  const int lane = threadIdx.x;
  if (bid < 768) {
    // Bf[nf*24+ks][lane]: n = nf*16 + (lane&15), k = ks*32 + (lane>>4)*8 + j
    const int nf = bid / 24, ks = bid % 24;
    const int n = nf*16 + (lane & 15);
    const int kb = ks*32 + (lane >> 4)*8;
    unsigned r0 = pack2bf(W[(size_t)(kb+0)*DD + n], W[(size_t)(kb+1)*DD + n]);
    unsigned r1 = pack2bf(W[(size_t)(kb+2)*DD + n], W[(size_t)(kb+3)*DD + n]);
    unsigned r2 = pack2bf(W[(size_t)(kb+4)*DD + n], W[(size_t)(kb+5)*DD + n]);
    unsigned r3 = pack2bf(W[(size_t)(kb+6)*DD + n], W[(size_t)(kb+7)*DD + n]);
    Bf[(size_t)bid*64 + lane] = make_uint4(r0, r1, r2, r3);
    return;
  }
  const int ks = bid - 768;          // 0..24
  const int p = lane & 15, seg = lane >> 4;
  float ssq = 0.f;
  for (int d = seg*128; d < seg*128 + 128; d += 4) {
    float4 v = *(const float4*)&prot[p*DD + d];
    ssq += v.x*v.x + v.y*v.y + v.z*v.z + v.w*v.w;
  }
  ssq += __shfl_xor(ssq, 16);
  ssq += __shfl_xor(ssq, 32);
  const float rnp = 1.f / fmaxf(sqrtf(ssq), 1e-12f);
  if (ks < 24) {
    float v[8];
    #pragma unroll
    for (int j = 0; j < 8; ++j) {
      const int k = ks*32 + seg*8 + j;
      const float* wr = W + (size_t)k * DD;
      const float* pr = prot + p * DD;
      float s = 0.f;
      for (int d = 0; d < DD; d += 4) {
        float4 a = *(const float4*)(wr + d);
        float4 b = *(const float4*)(pr + d);
        s += a.x*b.x + a.y*b.y + a.z*b.z + a.w*b.w;
      }
      v[j] = s * rnp;
    }
    Wpnb[ks*64 + lane] = make_uint4(pack2bf(v[0],v[1]), pack2bf(v[2],v[3]),
                                    pack2bf(v[4],v[5]), pack2bf(v[6],v[7]));
  } else {
    float s = 0.f;
    for (int d = seg*128; d < seg*128 + 128; ++d) s += bias[d] * prot[p*DD + d];
    s += __shfl_xor(s, 16);
    s += __shfl_xor(s, 32);
    if (lane < 16) bpn[lane] = s * rnp;
  }
}

// ---------- GEMM: BM=128, BN=512, BK=64, 8 waves (2m x 4n), B in LDS (shared) ----------
// grid 1024 (128-row slabs over both sides). B staged once per block per kt via
// global_load_lds (dbuf 2x64KB, issued at top of kt so MFMA covers the drain);
// A fp32->bf16 reg-staged, single-buffered 16KB. 144KB LDS, 1 block/CU.
__global__ __launch_bounds__(512, 2) void gemm_kernel(
    const float* __restrict__ Xs, const float* __restrict__ Xl,
    const uint4* __restrict__ Bf, const uint4* __restrict__ Wpnb,
    const float* __restrict__ bias, const float* __restrict__ bpn,
    u16* __restrict__ proj, u16* __restrict__ wbufe,
    float* __restrict__ rnormb, float* __restrict__ espart) {
  __shared__ __align__(16) unsigned char lds[147456];  // A:0..16K, B0:16K, B1:80K
  const int t = threadIdx.x, lane = t & 63, wid = t >> 6;
  const int wm = wid >> 2, wn = wid & 3;
  const int cl = lane & 15, cg = lane >> 4;
  const int m0g = blockIdx.x * 128;             // global row over both sides
  const float* Xb = (m0g < MTOT) ? Xs : Xl;     // 65536 % 128 == 0: no straddle
  const int m0l = m0g & (MTOT - 1);
  // A staging (proven wslot): thread covers row r, 4 float4 chunks of k
  const int r = t >> 2, c4 = t & 3;
  const float* gA = Xb + (size_t)(m0l + r) * DIN + c4 * 4;
  int wslot[4];
  #pragma unroll
  for (int q = 0; q < 4; ++q)
    wslot[q] = (((r>>4)*2 + (q>>1))*64 + ((q&1)*2 + (c4>>1))*16 + (r&15)) * 16 + (c4&1)*8;

  const bool do_score = (wn == 0);    // waves 0 (rows 0-63) and 4 (rows 64-127)
  f32x4 acc[4][8] = {};
  f32x4 sacc[4] = {};

#define STAGE_B(ktx, buf) \
  { _Pragma("unroll") \
    for (int q_ = 0; q_ < 8; ++q_) { \
      const int c_ = q_*8 + wid; \
      const uint4* src_ = Bf + ((size_t)((c_>>1)*24 + (ktx)*2 + (c_&1)))*64 + lane; \
      __builtin_amdgcn_global_load_lds( \
          (const __attribute__((address_space(1))) void*)src_, \
          (__attribute__((address_space(3))) void*)(lds + 16384 + (buf)*65536 + c_*1024 + lane*16), \
          16, 0, 0); \
    } }

  {  // prologue: B(kt0) -> buf0, A(kt0) -> Albuf
    STAGE_B(0, 0);
    float4 va[4];
    #pragma unroll
    for (int q = 0; q < 4; ++q) va[q] = *(const float4*)(gA + q*16);
    #pragma unroll
    for (int q = 0; q < 4; ++q)
      *(uint2*)(&lds[wslot[q]]) =
          make_uint2(pack2bf(va[q].x, va[q].y), pack2bf(va[q].z, va[q].w));
    __syncthreads();
  }
  int cur = 0;
  for (int kt = 0; kt < 12; ++kt) {
    float4 va[4];
    if (kt < 11) {
      STAGE_B(kt + 1, cur ^ 1);       // issued early; drain covered by MFMAs below
      #pragma unroll
      for (int q = 0; q < 4; ++q) va[q] = *(const float4*)(gA + (kt+1)*64 + q*16);
    }
    const unsigned char* Bb = lds + 16384 + cur*65536;
    #pragma unroll
    for (int ksl = 0; ksl < 2; ++ksl) {
      bf16x8 af[4], bfr[8];
      #pragma unroll
      for (int i = 0; i < 4; ++i)
        af[i] = *(const bf16x8*)(&lds[(((wm*4 + i)*2 + ksl)*64 + lane)*16]);
      #pragma unroll
      for (int j = 0; j < 8; ++j)
        bfr[j] = *(const bf16x8*)(Bb + ((((wn*8 + j)<<1) | ksl)*64 + lane)*16);
      #pragma unroll
      for (int j = 0; j < 8; ++j)
        #pragma unroll
        for (int m = 0; m < 4; ++m)
          acc[m][j] = MFMA(af[m], bfr[j], acc[m][j]);
      if (do_score) {
        bf16x8 wf = *(const bf16x8*)(Wpnb + (kt*2 + ksl)*64 + lane);
        #pragma unroll
        for (int m = 0; m < 4; ++m) sacc[m] = MFMA(af[m], wf, sacc[m]);
      }
    }
    __syncthreads();                  // reads done; B(kt+1) drained here
    if (kt < 11) {
      #pragma unroll
      for (int q = 0; q < 4; ++q)
        *(uint2*)(&lds[wslot[q]]) =
            make_uint2(pack2bf(va[q].x, va[q].y), pack2bf(va[q].z, va[q].w));
      __syncthreads();                // A visible
    }
    cur ^= 1;
  }
#undef STAGE_B
  // ---- epilogue (reuses LDS after final barrier) ----
  float* ssqred = (float*)lds;                    // [128][4]
  float* rnl    = (float*)(lds + 2048);           // [128]
  float* esp2   = (float*)(lds + 2560);           // [2][16]
  u16*   sbuf   = (u16*)  (lds + 2688);           // [16][128]
  float bv[8];
  #pragma unroll
  for (int j = 0; j < 8; ++j) bv[j] = bias[wn*128 + j*16 + cl];
  #pragma unroll
  for (int m = 0; m < 4; ++m) {
    #pragma unroll
    for (int rr = 0; rr < 4; ++rr) {
      const int rowl = wm*64 + m*16 + cg*4 + rr;
      u16* pr = proj + (size_t)(m0g + rowl) * DD + wn*128 + cl;
      float sq = 0.f;
      #pragma unroll
      for (int j = 0; j < 8; ++j) {
        float val = acc[m][j][rr] + bv[j];
        pr[j*16] = f2bf(val);
        sq += val * val;
      }
      sq += __shfl_xor(sq, 1); sq += __shfl_xor(sq, 2);
      sq += __shfl_xor(sq, 4); sq += __shfl_xor(sq, 8);
      if (cl == 0) ssqred[rowl*4 + wn] = sq;
    }
  }
  __syncthreads();
  if (t < 128) {
    float ss = ssqred[t*4+0] + ssqred[t*4+1] + ssqred[t*4+2] + ssqred[t*4+3];
    float rn = 1.f / fmaxf(sqrtf(ss), 1e-12f);
    rnl[t] = rn;
    rnormb[m0g + t] = rn;
  }
  __syncthreads();
  if (do_score) {
    const float bpv = bpn[cl];
    float esum = 0.f;
    #pragma unroll
    for (int m = 0; m < 4; ++m)
      #pragma unroll
      for (int rr = 0; rr < 4; ++rr) {
        const int rowl = wm*64 + m*16 + cg*4 + rr;
        const float sc = (sacc[m][rr] + bpv) * rnl[rowl] * SCALE_INV_SQRT_D;
        const float e = expf(sc);     // |sc| <= ~0.0442: no max-subtract needed
        esum += e;
        sbuf[cl*128 + rowl] = f2bf(e);
      }
    esum += __shfl_xor(esum, 16);
    esum += __shfl_xor(esum, 32);
    if (cg == 0) esp2[wm*16 + cl] = esum;
  }
  __syncthreads();
  if (t < 16) espart[(size_t)blockIdx.x * PP + t] = esp2[t] + esp2[16 + t];
  {  // coalesced wbufe store: 4 u16 per thread, one 256B p-row per 32 threads
    const int p = t >> 5, i4 = (t & 31) * 4;
    const int sbp = m0g >> 15, nb0 = m0g & (NN - 1);
    *(uint2*)&wbufe[(size_t)(sbp*PP + p) * NN + nb0 + i4] =
        *(const uint2*)&sbuf[p*128 + i4];
  }
}

// ---------- reduce expsum partials -> iSrow[(side*2+b)*16+p]: grid 64 ----------
__global__ __launch_bounds__(256) void isum_kernel(const float* __restrict__ espart,
                                                   float* __restrict__ iSrow) {
  __shared__ float sred[4];
  const int bid = blockIdx.x, sbp = bid >> 4, p = bid & 15;
  const int t = threadIdx.x;
  float s = espart[(size_t)(sbp*256 + t)*PP + p];
  s = block_reduce_sum_256(s, sred);
  if (t == 0) iSrow[bid] = 1.f / s;
}

// ---------- attended (fused wsum), both sides: grid (NCHUNK, 4) ----------
__global__ __launch_bounds__(256) void attended_kernel(
    const u16* __restrict__ proj, const u16* __restrict__ wbufe,
    const float* __restrict__ rnormb, const float* __restrict__ iSrow,
    float* __restrict__ part) {
  __shared__ float wl[CHUNK];
  __shared__ float iSl[PP];
  const int sb = blockIdx.y, cid = blockIdx.x, t = threadIdx.x;
  const int nbase = cid * CHUNK;
  if (t < PP) iSl[t] = iSrow[sb*PP + t];
  __syncthreads();
  if (t < CHUNK) {
    const int n = nbase + t;
    float s = 0.f;
    #pragma unroll
    for (int p = 0; p < PP; ++p)
      s += bf2f(wbufe[(size_t)(sb*PP + p)*NN + n]) * iSl[p];
    wl[t] = s * rnormb[sb*NN + n] * (1.f / PP);
  }
  __syncthreads();
  float a0 = 0.f, a1 = 0.f;
  const u16* pb = proj + ((size_t)sb * NN + nbase) * DD + 2*t;
  #pragma unroll 8
  for (int n = 0; n < CHUNK; ++n) {
    unsigned uu = *(const unsigned*)(pb + (size_t)n * DD);
    float w = wl[n];
    a0 += w * bf2f((u16)uu);
    a1 += w * bf2f((u16)(uu >> 16));
  }
  *(float2*)&part[((size_t)(sb*NCHUNK + cid))*DD + 2*t] = make_float2(a0, a1);
}

// ---------- reduce chunks -> fraw[sb][d]: grid (4 dchunks, 4 sb) ----------
__global__ __launch_bounds__(256) void featred_kernel(
    const float* __restrict__ part, float* __restrict__ fraw) {
  __shared__ float red[2][128];
  const int sb = blockIdx.y, d0 = blockIdx.x * 128, t = threadIdx.x;
  const int dl = t & 127, half = t >> 7;
  float s = 0.f;
  for (int c = half*64; c < half*64 + 64; ++c)
    s += part[((size_t)(sb*NCHUNK + c))*DD + d0 + dl];
  red[half][dl] = s;
  __syncthreads();
  if (t < 128) fraw[sb*DD + d0 + t] = red[0][t] + red[1][t];
}

// ---------- final: normalize feats, logits, softmax, argmax, loss ----------
__global__ __launch_bounds__(256) void final_kernel(
    const float* __restrict__ fraw, const float* __restrict__ textL,
    const float* __restrict__ textH, const int* __restrict__ label,
    float* __restrict__ out) {
  __shared__ float sred[4];
  const int t = threadIdx.x;
  const float* frawL = fraw;            // sb 0,1 = x_s b0,b1
  const float* frawH = fraw + 2*DD;     // sb 2,3 = x_l b0,b1
  float invL[2], invH[2];
  #pragma unroll
  for (int b = 0; b < 2; ++b) {
    float v = 0.f;
    for (int d = t; d < DD; d += 256) { float x = frawL[b*DD + d]; v += x*x; }
    float ss = block_reduce_sum_256(v, sred);
    invL[b] = 1.f / fmaxf(sqrtf(ss), 1e-12f);
    v = 0.f;
    for (int d = t; d < DD; d += 256) { float x = frawH[b*DD + d]; v += x*x; }
    ss = block_reduce_sum_256(v, sred);
    invH[b] = 1.f / fmaxf(sqrtf(ss), 1e-12f);
  }
  float lg[2][2];
  #pragma unroll
  for (int b = 0; b < 2; ++b)
    #pragma unroll
    for (int c = 0; c < 2; ++c) {
      float v = 0.f;
      for (int d = t; d < DD; d += 256)
        v += frawL[b*DD + d] * invL[b] * textL[c*DD + d]
           + frawH[b*DD + d] * invH[b] * textH[c*DD + d];
      lg[b][c] = block_reduce_sum_256(v, sred);
    }
  if (t == 0) {
    float loss = 0.f;
    #pragma unroll
    for (int b = 0; b < 2; ++b) {
      const float m  = fmaxf(lg[b][0], lg[b][1]);
      const float lse = m + logf(expf(lg[b][0]-m) + expf(lg[b][1]-m));
      out[b*2+0] = expf(lg[b][0]-lse); out[b*2+1] = expf(lg[b][1]-lse);
      out[4+b] = (lg[b][1] > lg[b][0]) ? 1.f : 0.f;
      loss += -(lg[b][label[b]] - lse);
    }
    out[6] = loss * 0.5f;
  }
}

extern "C" void kernel_launch(void* const* d_in, const int* in_sizes, int n_in,
                              void* d_out, int out_size, void* d_ws, size_t ws_size,
                              hipStream_t stream) {
  (void)in_sizes; (void)n_in; (void)out_size; (void)ws_size;
  const float* x_s  = (const float*)d_in[0];
  const float* x_l  = (const float*)d_in[2];
  const float* Wp   = (const float*)d_in[4];
  const float* bp   = (const float*)d_in[5];
  const float* prot = (const float*)d_in[6];
  const float* tL   = (const float*)d_in[7];
  const float* tH   = (const float*)d_in[8];
  const int*   label= (const int*)d_in[9];
  float* out = (float*)d_out;

  unsigned char* w8 = (unsigned char*)d_ws;
  u16*   proj   = (u16*)  (w8);                  // 134,217,728 (both sides)
  u16*   wbufe  = (u16*)  (w8 + 134217728);      //   4,194,304  exp(score) bf16 [4][16][NN]
  float* part   = (float*)(w8 + 138412032);      //   1,048,576  [4][NCHUNK][DD]
  float* rnormb = (float*)(w8 + 139460608);      //     524,288  [131072]
  float* espart = (float*)(w8 + 139984896);      //      65,536  [1024][16]
  float* iSrow  = (float*)(w8 + 140050432);      //       1,024
  uint4* Bf     = (uint4*)(w8 + 140051456);      //     786,432
  uint4* Wpnb   = (uint4*)(w8 + 140837888);      //      24,576
  float* bpn    = (float*)(w8 + 140862464);      //       1,024
  float* fraw   = (float*)(w8 + 140863488);      //       8,192  [4][512]

  pre_kernel<<<793, 64, 0, stream>>>(Wp, prot, bp, Bf, Wpnb, bpn);
  gemm_kernel<<<MALL/128, 512, 0, stream>>>(x_s, x_l, Bf, Wpnb, bp, bpn,
                                            proj, wbufe, rnormb, espart);
  isum_kernel<<<64, 256, 0, stream>>>(espart, iSrow);
  attended_kernel<<<dim3(NCHUNK, 4), 256, 0, stream>>>(proj, wbufe, rnormb, iSrow, part);
  featred_kernel<<<dim3(4, 4), 256, 0, stream>>>(part, fraw);
  final_kernel<<<1, 256, 0, stream>>>(fraw, tL, tH, label, out);
}

// Round 11
// 250.089 us; speedup vs baseline: 1.7572x; 1.0797x over previous
//
#include <hip/hip_runtime.h>
#include <math.h>

#define BB   2
#define NN   32768
#define DIN  768
#define DD   512
#define PP   16
#define MTOT (BB*NN)          // rows per side
#define MALL (2*MTOT)         // both sides
#define NCHUNK 128
#define CHUNK  (NN/NCHUNK)    // 256
#define SCALE_INV_SQRT_D 0.04419417382415922f  // 1/sqrt(512)

typedef unsigned short u16;
typedef __attribute__((ext_vector_type(8))) short bf16x8;
typedef __attribute__((ext_vector_type(4))) float f32x4;

#define MFMA(a,b,c) __builtin_amdgcn_mfma_f32_16x16x32_bf16((a),(b),(c),0,0,0)

__device__ __forceinline__ unsigned pack2bf(float a, float b) {
  union { float f; unsigned u; } x{a}, y{b};
  unsigned ra = (x.u + 0x7FFFu + ((x.u >> 16) & 1u)) >> 16;
  unsigned rb = (y.u + 0x7FFFu + ((y.u >> 16) & 1u)) >> 16;
  return ra | (rb << 16);
}
__device__ __forceinline__ u16 f2bf(float a) {
  union { float f; unsigned u; } x{a};
  return (u16)((x.u + 0x7FFFu + ((x.u >> 16) & 1u)) >> 16);
}
__device__ __forceinline__ float bf2f(u16 u) {
  union { unsigned u; float f; } x; x.u = ((unsigned)u) << 16; return x.f;
}

__device__ __forceinline__ float block_reduce_sum_256(float v, float* sred) {
  #pragma unroll
  for (int off = 32; off; off >>= 1) v += __shfl_down(v, off);
  const int lane = threadIdx.x & 63, w = threadIdx.x >> 6;
  if (lane == 0) sred[w] = v;
  __syncthreads();
  float r = sred[0] + sred[1] + sred[2] + sred[3];
  __syncthreads();
  return r;
}

// ---------- prepass: Bf pack (bid<768) | pnb pack with inline proto-norm ----------
__global__ __launch_bounds__(64) void pre_kernel(
    const float* __restrict__ W, const float* __restrict__ prot,
    uint4* __restrict__ Bf, uint4* __restrict__ pnb) {
  const int bid = blockIdx.x;
  const int lane = threadIdx.x;
  if (bid < 768) {
    // Bf[nf*24+ks][lane]: n = nf*16 + (lane&15), k = ks*32 + (lane>>4)*8 + j
    const int nf = bid / 24, ks = bid % 24;
    const int n = nf*16 + (lane & 15);
    const int kb = ks*32 + (lane >> 4)*8;
    unsigned r0 = pack2bf(W[(size_t)(kb+0)*DD + n], W[(size_t)(kb+1)*DD + n]);
    unsigned r1 = pack2bf(W[(size_t)(kb+2)*DD + n], W[(size_t)(kb+3)*DD + n]);
    unsigned r2 = pack2bf(W[(size_t)(kb+4)*DD + n], W[(size_t)(kb+5)*DD + n]);
    unsigned r3 = pack2bf(W[(size_t)(kb+6)*DD + n], W[(size_t)(kb+7)*DD + n]);
    Bf[(size_t)bid*64 + lane] = make_uint4(r0, r1, r2, r3);
    return;
  }
  // pnb[ks 0..15][lane]: p = lane&15, k = ks*32 + (lane>>4)*8 + j, normalized
  const int ks = bid - 768;
  const int p = lane & 15, seg = lane >> 4;
  float ssq = 0.f;
  for (int d = seg*128; d < seg*128 + 128; d += 4) {
    float4 v = *(const float4*)&prot[p*DD + d];
    ssq += v.x*v.x + v.y*v.y + v.z*v.z + v.w*v.w;
  }
  ssq += __shfl_xor(ssq, 16);
  ssq += __shfl_xor(ssq, 32);
  const float rnp = 1.f / fmaxf(sqrtf(ssq), 1e-12f);
  const int kb = ks*32 + seg*8;
  float v[8];
  #pragma unroll
  for (int j = 0; j < 8; ++j) v[j] = prot[p*DD + kb + j] * rnp;
  pnb[ks*64 + lane] = make_uint4(pack2bf(v[0],v[1]), pack2bf(v[2],v[3]),
                                 pack2bf(v[4],v[5]), pack2bf(v[6],v[7]));
}

// ---------- GEMM: BM=64, BN=512, BK=32, 8 waves (1m x 8n), wave 64x64 ----------
// grid 2048 (64-row slabs, both sides). A+B full LDS dbuf (72KB -> 2 blocks/CU),
// one barrier/kt. acc[4][4]=64 AGPR + ~60 VGPR -> 4 waves/SIMD. No score fusion.
__global__ __launch_bounds__(512, 4) void gemm_kernel(
    const float* __restrict__ Xs, const float* __restrict__ Xl,
    const uint4* __restrict__ Bf, const float* __restrict__ bias,
    u16* __restrict__ proj, float* __restrict__ rnormb) {
  __shared__ __align__(16) unsigned char lds[73728];  // A: 2x4K @0, B: 2x32K @8K
  const int t = threadIdx.x, lane = t & 63, wn = t >> 6;   // 8 n-waves
  const int cl = lane & 15, cg = lane >> 4;
  const int m0g = blockIdx.x * 64;              // global row over both sides
  const float* Xb = (m0g < MTOT) ? Xs : Xl;     // 65536 % 64 == 0: no straddle
  const int m0l = m0g & (MTOT - 1);
  // A staging: r = t>>3 (64 rows), k = (t&7)*4 .. +4 (one float4/thread)
  const int r = t >> 3, c4 = t & 7;
  const float* gA = Xb + (size_t)(m0l + r) * DIN + c4 * 4;
  const int awoff = (r >> 4)*1024 + ((r & 15) + 16*(c4 >> 1))*16 + (c4 & 1)*8;

  f32x4 acc[4][4] = {};

#define STAGE_B(ktx, buf) \
  { _Pragma("unroll") \
    for (int q_ = 0; q_ < 4; ++q_) { \
      const int c_ = q_*8 + wn; \
      const uint4* src_ = Bf + ((size_t)(c_*24 + (ktx)))*64 + lane; \
      __builtin_amdgcn_global_load_lds( \
          (const __attribute__((address_space(1))) void*)src_, \
          (__attribute__((address_space(3))) void*)(lds + 8192 + (buf)*32768 + c_*1024 + lane*16), \
          16, 0, 0); \
    } }

  {  // prologue: B(0)->buf0, A(0)->buf0
    STAGE_B(0, 0);
    float4 va = *(const float4*)gA;
    *(uint2*)(lds + awoff) = make_uint2(pack2bf(va.x, va.y), pack2bf(va.z, va.w));
  }
  __syncthreads();
  for (int kt = 0; kt < 24; ++kt) {
    const int cur = kt & 1;
    float4 va;
    if (kt < 23) {
      STAGE_B(kt + 1, cur ^ 1);                       // issue early
      va = *(const float4*)(gA + (kt + 1) * 32);      // issue early
    }
    bf16x8 af[4], bfr[4];
    #pragma unroll
    for (int m = 0; m < 4; ++m)
      af[m] = *(const bf16x8*)(lds + cur*4096 + m*1024 + lane*16);
    #pragma unroll
    for (int j = 0; j < 4; ++j)
      bfr[j] = *(const bf16x8*)(lds + 8192 + cur*32768 + (wn*4 + j)*1024 + lane*16);
    #pragma unroll
    for (int j = 0; j < 4; ++j)
      #pragma unroll
      for (int m = 0; m < 4; ++m)
        acc[m][j] = MFMA(af[m], bfr[j], acc[m][j]);
    if (kt < 23) {                                    // A write-late (HBM covered)
      *(uint2*)(lds + (cur^1)*4096 + awoff) =
          make_uint2(pack2bf(va.x, va.y), pack2bf(va.z, va.w));
    }
    __syncthreads();
  }
#undef STAGE_B
  // ---- epilogue: bias, proj bf16 store, ssq -> rnormb (reuse LDS) ----
  float* ssqred = (float*)lds;                  // [64][8]
  float bv[4];
  #pragma unroll
  for (int j = 0; j < 4; ++j) bv[j] = bias[wn*64 + j*16 + cl];
  #pragma unroll
  for (int m = 0; m < 4; ++m) {
    #pragma unroll
    for (int rr = 0; rr < 4; ++rr) {
      const int rowl = m*16 + cg*4 + rr;
      u16* pr = proj + (size_t)(m0g + rowl) * DD + wn*64 + cl;
      float sq = 0.f;
      #pragma unroll
      for (int j = 0; j < 4; ++j) {
        float val = acc[m][j][rr] + bv[j];
        pr[j*16] = f2bf(val);
        sq += val * val;
      }
      sq += __shfl_xor(sq, 1); sq += __shfl_xor(sq, 2);
      sq += __shfl_xor(sq, 4); sq += __shfl_xor(sq, 8);
      if (cl == 0) ssqred[rowl*8 + wn] = sq;
    }
  }
  __syncthreads();
  if (t < 64) {
    float ss = 0.f;
    #pragma unroll
    for (int w = 0; w < 8; ++w) ss += ssqred[t*8 + w];
    rnormb[m0g + t] = 1.f / fmaxf(sqrtf(ss), 1e-12f);
  }
}

// ---------- scores via MFMA: exp(score), espart, wbufe; grid 1024 x 256 thr ----------
__global__ __launch_bounds__(256) void scores_kernel(
    const u16* __restrict__ proj, const uint4* __restrict__ pnb,
    const float* __restrict__ rnormb, u16* __restrict__ wbufe,
    float* __restrict__ espart) {
  __shared__ float esp[4][16];
  __shared__ u16 sbuf[128][18];   // padded: write by col, read by row
  const int t = threadIdx.x, lane = t & 63, wave = t >> 6;
  const int cl = lane & 15, cg = lane >> 4;
  bf16x8 pf[16];
  #pragma unroll
  for (int ks = 0; ks < 16; ++ks) pf[ks] = *(const bf16x8*)(pnb + ks*64 + lane);
  const int row0b = blockIdx.x * 128;
  float esum = 0.f;
  #pragma unroll
  for (int rg = 0; rg < 2; ++rg) {
    const int row0 = row0b + wave*32 + rg*16;
    f32x4 sacc = {0.f, 0.f, 0.f, 0.f};
    #pragma unroll
    for (int ks = 0; ks < 16; ++ks) {
      bf16x8 af = *(const bf16x8*)(proj + (size_t)(row0 + cl)*DD + ks*32 + cg*8);
      sacc = MFMA(af, pf[ks], sacc);
    }
    #pragma unroll
    for (int rr = 0; rr < 4; ++rr) {
      const int grow = row0 + cg*4 + rr;
      const float sc = sacc[rr] * rnormb[grow] * SCALE_INV_SQRT_D;
      const float e = expf(sc);      // |sc| <= ~0.0442: no max-subtract needed
      esum += e;
      sbuf[wave*32 + rg*16 + cg*4 + rr][cl] = f2bf(e);
    }
  }
  esum += __shfl_xor(esum, 16);
  esum += __shfl_xor(esum, 32);
  if (lane < 16) esp[wave][lane] = esum;
  __syncthreads();
  if (t < 16)
    espart[(size_t)blockIdx.x * PP + t] = esp[0][t] + esp[1][t] + esp[2][t] + esp[3][t];
  {  // coalesced wbufe store: p = t>>4, 8 u16 per thread
    const int p = t >> 4, i8 = (t & 15) * 8;
    const int sbp = row0b >> 15, nb0 = row0b & (NN - 1);
    u16 tmp[8];
    #pragma unroll
    for (int k = 0; k < 8; ++k) tmp[k] = sbuf[i8 + k][p];
    *(uint4*)&wbufe[(size_t)(sbp*PP + p) * NN + nb0 + i8] = *(const uint4*)tmp;
  }
}

// ---------- reduce expsum partials -> iSrow[(side*2+b)*16+p]: grid 64 ----------
__global__ __launch_bounds__(256) void isum_kernel(const float* __restrict__ espart,
                                                   float* __restrict__ iSrow) {
  __shared__ float sred[4];
  const int bid = blockIdx.x, sbp = bid >> 4, p = bid & 15;
  const int t = threadIdx.x;
  float s = espart[(size_t)(sbp*256 + t)*PP + p];
  s = block_reduce_sum_256(s, sred);
  if (t == 0) iSrow[bid] = 1.f / s;
}

// ---------- attended (fused wsum), both sides: grid (NCHUNK, 4) ----------
__global__ __launch_bounds__(256) void attended_kernel(
    const u16* __restrict__ proj, const u16* __restrict__ wbufe,
    const float* __restrict__ rnormb, const float* __restrict__ iSrow,
    float* __restrict__ part) {
  __shared__ float wl[CHUNK];
  __shared__ float iSl[PP];
  const int sb = blockIdx.y, cid = blockIdx.x, t = threadIdx.x;
  const int nbase = cid * CHUNK;
  if (t < PP) iSl[t] = iSrow[sb*PP + t];
  __syncthreads();
  if (t < CHUNK) {
    const int n = nbase + t;
    float s = 0.f;
    #pragma unroll
    for (int p = 0; p < PP; ++p)
      s += bf2f(wbufe[(size_t)(sb*PP + p)*NN + n]) * iSl[p];
    wl[t] = s * rnormb[sb*NN + n] * (1.f / PP);
  }
  __syncthreads();
  float a0 = 0.f, a1 = 0.f;
  const u16* pb = proj + ((size_t)sb * NN + nbase) * DD + 2*t;
  #pragma unroll 8
  for (int n = 0; n < CHUNK; ++n) {
    unsigned uu = *(const unsigned*)(pb + (size_t)n * DD);
    float w = wl[n];
    a0 += w * bf2f((u16)uu);
    a1 += w * bf2f((u16)(uu >> 16));
  }
  *(float2*)&part[((size_t)(sb*NCHUNK + cid))*DD + 2*t] = make_float2(a0, a1);
}

// ---------- reduce chunks -> fraw[sb][d]: grid (4 dchunks, 4 sb) ----------
__global__ __launch_bounds__(256) void featred_kernel(
    const float* __restrict__ part, float* __restrict__ fraw) {
  __shared__ float red[2][128];
  const int sb = blockIdx.y, d0 = blockIdx.x * 128, t = threadIdx.x;
  const int dl = t & 127, half = t >> 7;
  float s = 0.f;
  for (int c = half*64; c < half*64 + 64; ++c)
    s += part[((size_t)(sb*NCHUNK + c))*DD + d0 + dl];
  red[half][dl] = s;
  __syncthreads();
  if (t < 128) fraw[sb*DD + d0 + t] = red[0][t] + red[1][t];
}

// ---------- final: normalize feats, logits, softmax, argmax, loss ----------
__global__ __launch_bounds__(256) void final_kernel(
    const float* __restrict__ fraw, const float* __restrict__ textL,
    const float* __restrict__ textH, const int* __restrict__ label,
    float* __restrict__ out) {
  __shared__ float sred[4];
  const int t = threadIdx.x;
  const float* frawL = fraw;            // sb 0,1 = x_s b0,b1
  const float* frawH = fraw + 2*DD;     // sb 2,3 = x_l b0,b1
  float invL[2], invH[2];
  #pragma unroll
  for (int b = 0; b < 2; ++b) {
    float v = 0.f;
    for (int d = t; d < DD; d += 256) { float x = frawL[b*DD + d]; v += x*x; }
    float ss = block_reduce_sum_256(v, sred);
    invL[b] = 1.f / fmaxf(sqrtf(ss), 1e-12f);
    v = 0.f;
    for (int d = t; d < DD; d += 256) { float x = frawH[b*DD + d]; v += x*x; }
    ss = block_reduce_sum_256(v, sred);
    invH[b] = 1.f / fmaxf(sqrtf(ss), 1e-12f);
  }
  float lg[2][2];
  #pragma unroll
  for (int b = 0; b < 2; ++b)
    #pragma unroll
    for (int c = 0; c < 2; ++c) {
      float v = 0.f;
      for (int d = t; d < DD; d += 256)
        v += frawL[b*DD + d] * invL[b] * textL[c*DD + d]
           + frawH[b*DD + d] * invH[b] * textH[c*DD + d];
      lg[b][c] = block_reduce_sum_256(v, sred);
    }
  if (t == 0) {
    float loss = 0.f;
    #pragma unroll
    for (int b = 0; b < 2; ++b) {
      const float m  = fmaxf(lg[b][0], lg[b][1]);
      const float lse = m + logf(expf(lg[b][0]-m) + expf(lg[b][1]-m));
      out[b*2+0] = expf(lg[b][0]-lse); out[b*2+1] = expf(lg[b][1]-lse);
      out[4+b] = (lg[b][1] > lg[b][0]) ? 1.f : 0.f;
      loss += -(lg[b][label[b]] - lse);
    }
    out[6] = loss * 0.5f;
  }
}

extern "C" void kernel_launch(void* const* d_in, const int* in_sizes, int n_in,
                              void* d_out, int out_size, void* d_ws, size_t ws_size,
                              hipStream_t stream) {
  (void)in_sizes; (void)n_in; (void)out_size; (void)ws_size;
  const float* x_s  = (const float*)d_in[0];
  const float* x_l  = (const float*)d_in[2];
  const float* Wp   = (const float*)d_in[4];
  const float* bp   = (const float*)d_in[5];
  const float* prot = (const float*)d_in[6];
  const float* tL   = (const float*)d_in[7];
  const float* tH   = (const float*)d_in[8];
  const int*   label= (const int*)d_in[9];
  float* out = (float*)d_out;

  unsigned char* w8 = (unsigned char*)d_ws;
  u16*   proj   = (u16*)  (w8);                  // 134,217,728 (both sides)
  u16*   wbufe  = (u16*)  (w8 + 134217728);      //   4,194,304  exp(score) bf16 [4][16][NN]
  float* part   = (float*)(w8 + 138412032);      //   1,048,576  [4][NCHUNK][DD]
  float* rnormb = (float*)(w8 + 139460608);      //     524,288  [131072]
  float* espart = (float*)(w8 + 139984896);      //      65,536  [1024][16]
  float* iSrow  = (float*)(w8 + 140050432);      //       1,024
  uint4* Bf     = (uint4*)(w8 + 140051456);      //     786,432
  uint4* pnb    = (uint4*)(w8 + 140837888);      //      16,384
  float* fraw   = (float*)(w8 + 140854272);      //       8,192  [4][512]

  pre_kernel<<<784, 64, 0, stream>>>(Wp, prot, Bf, pnb);
  gemm_kernel<<<MALL/64, 512, 0, stream>>>(x_s, x_l, Bf, bp, proj, rnormb);
  scores_kernel<<<MALL/128, 256, 0, stream>>>(proj, pnb, rnormb, wbufe, espart);
  isum_kernel<<<64, 256, 0, stream>>>(espart, iSrow);
  attended_kernel<<<dim3(NCHUNK, 4), 256, 0, stream>>>(proj, wbufe, rnormb, iSrow, part);
  featred_kernel<<<dim3(4, 4), 256, 0, stream>>>(part, fraw);
  final_kernel<<<1, 256, 0, stream>>>(fraw, tL, tH, label, out);
}